// Round 11
// baseline (174.115 us; speedup 1.0000x reference)
//
#include <hip/hip_runtime.h>
#include <math.h>

typedef _Float16 h8 __attribute__((ext_vector_type(8)));
typedef _Float16 h4 __attribute__((ext_vector_type(4)));
typedef float    f4 __attribute__((ext_vector_type(4)));

#define NPAIR (8*256*256)
#define NTILE (NPAIR/16)          // 32768 tiles of 16 rows
#define BLOCKS 768                // 3 blocks/CU * 256 CUs: fully persistent grid
#define NWAVE (BLOCKS*4)          // 3072 waves, grid-stride over tiles

#define MFMA(a,b,c) __builtin_amdgcn_mfma_f32_16x16x32_f16((a),(b),(c),0,0,0)
// Compiler-order fence: our stage chaining is cross-lane LDS write->read within
// a wave (correct only if compiler preserves program order; HW DS is per-wave
// FIFO). Zero instructions emitted.
#define FENCE() asm volatile("" ::: "memory")

// Weight fragments (h8 units). k-indices of W2/Wg1 are PERMUTED to match the
// packed LDS layouts (reduction order over k is arbitrary as long as A and B
// agree):
//   h tile:  position p = (u%16)*4 + u/16        (u = hidden 0..63)
//   e tile:  position p = (u%16)*8 + (u/64)*4 + (u/16)%4   (u = 0..127)
// [0,256)    W1   [t*64+lane]   k 9..31 zero-padded (natural k order)
// [256,768)  W2   [c*256+t*64+lane]   k = k_h(32c+8q+j)
// [896,1920) Wg1  [c*256+t*64+lane]   k = k_e(32c+8q+j)
__device__ h8 g_all[1920];
__device__ float g_cc[2];         // C0 = sum ln_b*Wo, C1 = sum ln_g*Wo

__global__ void prep_kernel(const float* __restrict__ W1, const float* __restrict__ W2,
                            const float* __restrict__ Wg1, const float* __restrict__ Wg2,
                            const float* __restrict__ ln_g, const float* __restrict__ ln_b,
                            const float* __restrict__ Wo)
{
    int idx = blockIdx.x * 256 + threadIdx.x;
    if (idx < 256) {
        int t = idx >> 6, lane = idx & 63, q = lane >> 4, nn = lane & 15;
        h8 v;
#pragma unroll
        for (int j = 0; j < 8; ++j) { int k = 8*q + j; v[j] = (_Float16)((k < 9) ? W1[k*64 + 16*t + nn] : 0.f); }
        g_all[idx] = v;
    } else if (idx < 768) {
        int z = idx - 256; int c = z >> 8, t = (z >> 6) & 3, lane = z & 63, q = lane >> 4, nn = lane & 15;
        h8 v;
#pragma unroll
        for (int j = 0; j < 8; ++j) {
            int p = 32*c + 8*q + j;                 // position in packed h tile
            int k = (p >> 2) + 16*(p & 3);          // logical hidden index
            v[j] = (_Float16)W2[k*64 + 16*t + nn];
        }
        g_all[idx] = v;
    } else if (idx >= 896 && idx < 1920) {
        int z = idx - 896; int c = z >> 8, t = (z >> 6) & 3, lane = z & 63, q = lane >> 4, nn = lane & 15;
        h8 v;
#pragma unroll
        for (int j = 0; j < 8; ++j) {
            int p = 32*c + 8*q + j;                 // position in packed e tile
            int k = ((p >> 2) & 1)*64 + (p & 3)*16 + (p >> 3);
            v[j] = (_Float16)Wg1[k*64 + 16*t + nn];
        }
        g_all[idx] = v;
    } else if (idx == 1920) {
        float c0 = 0.f, c1 = 0.f;
        for (int k = 0; k < 64; ++k) { c0 += ln_b[k]*Wo[k]; c1 += ln_g[k]*Wo[k]; }
        g_cc[0] = c0; g_cc[1] = c1;
    }
}

__device__ __forceinline__ float sig(float x) { return __builtin_amdgcn_rcpf(1.f + __expf(-x)); }

__device__ __forceinline__ f4 silu4(f4 v)
{
    f4 r; r[0] = v[0]*sig(v[0]); r[1] = v[1]*sig(v[1]); r[2] = v[2]*sig(v[2]); r[3] = v[3]*sig(v[3]);
    return r;
}

// 16-lane reduction on the VALU pipe via DPP row_ror (rows of 16 = our groups).
template<int C>
__device__ __forceinline__ float rora(float x)
{
    int y = __builtin_amdgcn_update_dpp(0, __float_as_int(x), C, 0xF, 0xF, true);
    return x + __int_as_float(y);
}
__device__ __forceinline__ float red16s(float x)
{
    x = rora<0x121>(x);  // row_ror:1
    x = rora<0x122>(x);  // row_ror:2
    x = rora<0x124>(x);  // row_ror:4
    x = rora<0x128>(x);  // row_ror:8
    return x;
}
__device__ __forceinline__ f4 red16(f4 v)
{ v[0] = red16s(v[0]); v[1] = red16s(v[1]); v[2] = red16s(v[2]); v[3] = red16s(v[3]); return v; }

// R11: R10's occupancy-3 plan with R9's f32 fuse/LN restored. R10's failure
// (absmax 0.57) was the f16-e fuse: LN divides by per-row std, so rows with
// std/|mu| < ~3e-2 amplify the f16 quantization noise in E[x^2]-mu^2
// catastrophically. Fuse/LN must run on the f32 MFMA frags (R9 numerics).
// Register slimming kept: W1/W2 B-frags from the LDS pool per-iter (laundered
// vs LICM), b2 folded into FiLM beta, no er reads. Peak ~145 regs < cap 168.
// LDS: 28672 pool + 4*4608 = 47104 -> 3 blocks/CU = 3 waves/SIMD.
__global__ __launch_bounds__(256, 3) void fused_kernel(
    const float* __restrict__ coords, const float* __restrict__ cost,
    const float* __restrict__ lscale, const float* __restrict__ b1,
    const float* __restrict__ b2, const float* __restrict__ fgam,
    const float* __restrict__ fbet, const float* __restrict__ bg1,
    const float* __restrict__ bg2, const float* __restrict__ Wg2,
    const float* __restrict__ gt, const float* __restrict__ lng,
    const float* __restrict__ Wo, const float* __restrict__ bo,
    float* __restrict__ out)
{
    __shared__ __align__(16) char smem[28672 + 4*4608];
    const int tid = threadIdx.x;
    const int wave = tid >> 6, lane = tid & 63;
    const int q = lane >> 4, nn = lane & 15;

    h8* wp = (h8*)smem;                       // [0,1024) Wg1, [1024,1280) W1, [1280,1792) W2
    for (int z = tid; z < 1024; z += 256) wp[z] = g_all[896 + z];
    for (int z = tid; z < 768;  z += 256) wp[1024 + z] = g_all[z];
    __syncthreads();

    _Float16* U = (_Float16*)(smem + 28672 + wave*4608);  // aliased feat/h/e

    const float b1c0 = b1[nn], b1c1 = b1[16+nn], b1c2 = b1[32+nn], b1c3 = b1[48+nn];
    const float fg00 = fgam[nn], fg01 = fgam[16+nn], fg02 = fgam[32+nn], fg03 = fgam[48+nn];
    const float fg10 = fgam[64+nn], fg11 = fgam[80+nn], fg12 = fgam[96+nn], fg13 = fgam[112+nn];
    // FiLM beta with b2 folded in: e = acc*fg + (b2*fg + fb)
    const float fb00 = fmaf(b2[nn],    fg00, fbet[nn]);
    const float fb01 = fmaf(b2[16+nn], fg01, fbet[16+nn]);
    const float fb02 = fmaf(b2[32+nn], fg02, fbet[32+nn]);
    const float fb03 = fmaf(b2[48+nn], fg03, fbet[48+nn]);
    const float fb10 = fmaf(b2[nn],    fg10, fbet[64+nn]);
    const float fb11 = fmaf(b2[16+nn], fg11, fbet[80+nn]);
    const float fb12 = fmaf(b2[32+nn], fg12, fbet[96+nn]);
    const float fb13 = fmaf(b2[48+nn], fg13, fbet[112+nn]);
    const float bgc0 = bg1[nn], bgc1 = bg1[16+nn], bgc2 = bg1[32+nn], bgc3 = bg1[48+nn];
    const float gw0 = lng[nn]*Wo[nn], gw1 = lng[16+nn]*Wo[16+nn];
    const float gw2 = lng[32+nn]*Wo[32+nn], gw3 = lng[48+nn]*Wo[48+nn];
    const float wd0 = Wg2[nn*2+1]      - Wg2[nn*2];
    const float wd1 = Wg2[(16+nn)*2+1] - Wg2[(16+nn)*2];
    const float wd2 = Wg2[(32+nn)*2+1] - Wg2[(32+nn)*2];
    const float wd3 = Wg2[(48+nn)*2+1] - Wg2[(48+nn)*2];
    const float dlgb = bg2[1] - bg2[0];
    const float s0 = __expf(lscale[0]), s1 = __expf(lscale[1]);
    const float invT = __expf(-gt[0]);
    const float outc = g_cc[0] + bo[0], C1 = g_cc[1];

    for (int T = blockIdx.x*4 + wave; T < NTILE; T += NWAVE) {
        const int p0 = T*16;
        const int bb = p0 >> 16, ii = (p0 >> 8) & 255, j0 = p0 & 255;
        // ---- features: lanes 0-15 cost channel, 16-31 angle channel ----
        const float xc = cost[p0 + nn];
        const float* cb = coords + (bb << 9);
        const float xi = cb[2*ii], yi = cb[2*ii+1];
        const float xj = cb[2*(j0+nn)], yj = cb[2*(j0+nn)+1];
        const float ang = atan2f(yi - yj, xi - xj);
        const int isA = q & 1;
        const float xv = isA ? ang : xc;
        const float sE = isA ? s1 : s0;
        FENCE();                               // prior-iter LDS reads stay above
        if (lane < 32) {
            _Float16* fp = U + isA*640 + nn*40;
            h8 r0; r0[0]=(_Float16)(xv*sE);
            r0[1]=(_Float16)(__sinf(xv)*sE);     r0[2]=(_Float16)(__cosf(xv)*sE);
            r0[3]=(_Float16)(__sinf(2.f*xv)*sE); r0[4]=(_Float16)(__cosf(2.f*xv)*sE);
            r0[5]=(_Float16)(__sinf(4.f*xv)*sE); r0[6]=(_Float16)(__cosf(4.f*xv)*sE);
            r0[7]=(_Float16)(__sinf(8.f*xv)*sE);
            h8 rz = (h8)(_Float16)0.f;
            h8 r1 = rz; r1[0]=(_Float16)(__cosf(8.f*xv)*sE);
            *(h8*)(fp)    = r0; *(h8*)(fp+8)  = r1;
            *(h8*)(fp+16) = rz; *(h8*)(fp+24) = rz;
        }
        FENCE();                               // feat writes before L1 reads
        // launder the LDS weight-pool index so per-iter reads can't be LICM'd
        // back into persistent registers (would blow the bounds-3 cap)
        int wofs = 0; asm volatile("" : "+s"(wofs));
        const h8* wpl = wp + wofs;
        // ---- L1: feats @ W1 -> silu -> packed h tile (pos = (u%16)*4+u/16) ----
        h8 aF0 = *(h8*)(U + nn*40 + q*8);
        h8 aF1 = *(h8*)(U + 640 + nn*40 + q*8);
        {
            h8 u0 = wpl[1024+lane], u1 = wpl[1088+lane], u2 = wpl[1152+lane], u3 = wpl[1216+lane];
            {
                f4 c0={b1c0,b1c0,b1c0,b1c0}, c1={b1c1,b1c1,b1c1,b1c1};
                f4 c2={b1c2,b1c2,b1c2,b1c2}, c3={b1c3,b1c3,b1c3,b1c3};
                c0=MFMA(aF0,u0,c0); c1=MFMA(aF0,u1,c1); c2=MFMA(aF0,u2,c2); c3=MFMA(aF0,u3,c3);
                c0=silu4(c0); c1=silu4(c1); c2=silu4(c2); c3=silu4(c3);
                _Float16* hb = U + (q*4)*72 + nn*4;
#pragma unroll
                for (int r = 0; r < 4; ++r) {
                    h4 pk; pk[0]=(_Float16)c0[r]; pk[1]=(_Float16)c1[r]; pk[2]=(_Float16)c2[r]; pk[3]=(_Float16)c3[r];
                    *(h4*)(hb + r*72) = pk;        // ds_write_b64
                }
            }
            {
                f4 c0={b1c0,b1c0,b1c0,b1c0}, c1={b1c1,b1c1,b1c1,b1c1};
                f4 c2={b1c2,b1c2,b1c2,b1c2}, c3={b1c3,b1c3,b1c3,b1c3};
                c0=MFMA(aF1,u0,c0); c1=MFMA(aF1,u1,c1); c2=MFMA(aF1,u2,c2); c3=MFMA(aF1,u3,c3);
                c0=silu4(c0); c1=silu4(c1); c2=silu4(c2); c3=silu4(c3);
                _Float16* hb = U + 1152 + (q*4)*72 + nn*4;
#pragma unroll
                for (int r = 0; r < 4; ++r) {
                    h4 pk; pk[0]=(_Float16)c0[r]; pk[1]=(_Float16)c1[r]; pk[2]=(_Float16)c2[r]; pk[3]=(_Float16)c3[r];
                    *(h4*)(hb + r*72) = pk;
                }
            }
        }
        FENCE();                               // h writes before L2 reads
        // ---- L2: h @ W2' (zero C-init; b2 in fb), FiLM; E stays f32 to fuse ----
        f4 E00,E01,E02,E03,E10,E11,E12,E13;
        {
            h8 a00 = *(h8*)(U + nn*72 + q*8);
            h8 a01 = *(h8*)(U + nn*72 + 32 + q*8);
            h8 a10 = *(h8*)(U + 1152 + nn*72 + q*8);
            h8 a11 = *(h8*)(U + 1152 + nn*72 + 32 + q*8);
            f4 z4 = {0.f,0.f,0.f,0.f};
            h8 v0 = wpl[1280+lane], v1 = wpl[1344+lane], v2 = wpl[1408+lane], v3 = wpl[1472+lane];
            E00=MFMA(a00,v0,z4); E01=MFMA(a00,v1,z4); E02=MFMA(a00,v2,z4); E03=MFMA(a00,v3,z4);
            E10=MFMA(a10,v0,z4); E11=MFMA(a10,v1,z4); E12=MFMA(a10,v2,z4); E13=MFMA(a10,v3,z4);
            h8 v4 = wpl[1536+lane], v5 = wpl[1600+lane], v6 = wpl[1664+lane], v7 = wpl[1728+lane];
            E00=MFMA(a01,v4,E00); E01=MFMA(a01,v5,E01); E02=MFMA(a01,v6,E02); E03=MFMA(a01,v7,E03);
            E10=MFMA(a11,v4,E10); E11=MFMA(a11,v5,E11); E12=MFMA(a11,v6,E12); E13=MFMA(a11,v7,E13);
            E00 = E00*fg00 + fb00; E01 = E01*fg01 + fb01; E02 = E02*fg02 + fb02; E03 = E03*fg03 + fb03;
            E10 = E10*fg10 + fb10; E11 = E11*fg11 + fb11; E12 = E12*fg12 + fb12; E13 = E13*fg13 + fb13;
            _Float16* eb = U + (q*4)*136 + nn*8;   // pos = (u%16)*8 + enc*4 + t
#pragma unroll
            for (int r = 0; r < 4; ++r) {
                h8 pk;
                pk[0]=(_Float16)E00[r]; pk[1]=(_Float16)E01[r]; pk[2]=(_Float16)E02[r]; pk[3]=(_Float16)E03[r];
                pk[4]=(_Float16)E10[r]; pk[5]=(_Float16)E11[r]; pk[6]=(_Float16)E12[r]; pk[7]=(_Float16)E13[r];
                *(h8*)(eb + r*136) = pk;           // ds_write_b128
            }
        }
        FENCE();                               // e writes before gate1 reads
        // ---- gate1: e-tile @ Wg1' + bg1 -> silu; gate2 in VALU ----
        h8 ae0 = *(h8*)(U + nn*136 + q*8);
        h8 ae1 = *(h8*)(U + nn*136 + 32 + q*8);
        h8 ae2 = *(h8*)(U + nn*136 + 64 + q*8);
        h8 ae3 = *(h8*)(U + nn*136 + 96 + q*8);
        f4 g0={bgc0,bgc0,bgc0,bgc0}, g1={bgc1,bgc1,bgc1,bgc1};
        f4 g2={bgc2,bgc2,bgc2,bgc2}, g3={bgc3,bgc3,bgc3,bgc3};
        g0=MFMA(ae0,wpl[lane],g0);     g0=MFMA(ae1,wpl[256+lane],g0); g0=MFMA(ae2,wpl[512+lane],g0); g0=MFMA(ae3,wpl[768+lane],g0);
        g1=MFMA(ae0,wpl[64+lane],g1);  g1=MFMA(ae1,wpl[320+lane],g1); g1=MFMA(ae2,wpl[576+lane],g1); g1=MFMA(ae3,wpl[832+lane],g1);
        g2=MFMA(ae0,wpl[128+lane],g2); g2=MFMA(ae1,wpl[384+lane],g2); g2=MFMA(ae2,wpl[640+lane],g2); g2=MFMA(ae3,wpl[896+lane],g2);
        g3=MFMA(ae0,wpl[192+lane],g3); g3=MFMA(ae1,wpl[448+lane],g3); g3=MFMA(ae2,wpl[704+lane],g3); g3=MFMA(ae3,wpl[960+lane],g3);
        g0=silu4(g0); g1=silu4(g1); g2=silu4(g2); g3=silu4(g3);
        // gate2 in VALU: per-row logit diff = red16 of per-lane partials
        f4 part = g0*wd0 + g1*wd1 + g2*wd2 + g3*wd3;
        f4 diff = red16(part);
        f4 w1v;
        w1v[0] = sig((diff[0]+dlgb)*invT); w1v[1] = sig((diff[1]+dlgb)*invT);
        w1v[2] = sig((diff[2]+dlgb)*invT); w1v[3] = sig((diff[3]+dlgb)*invT);
        // ---- fuse + LayerNorm + head from the f32 E-frags (R9 numerics) ----
        f4 fu0 = E00 + w1v*(E10-E00);
        f4 fu1 = E01 + w1v*(E11-E01);
        f4 fu2 = E02 + w1v*(E12-E02);
        f4 fu3 = E03 + w1v*(E13-E03);
        f4 sv = red16((fu0+fu1)+(fu2+fu3));
        f4 sq = red16((fu0*fu0+fu1*fu1)+(fu2*fu2+fu3*fu3));
        f4 dt = red16((fu0*gw0 + fu1*gw1) + (fu2*gw2 + fu3*gw3));
        f4 mu = sv * (1.f/64.f);
        f4 vv = sq * (1.f/64.f) - mu*mu;
        f4 rs;
        rs[0] = __builtin_amdgcn_rsqf(vv[0]+1e-5f); rs[1] = __builtin_amdgcn_rsqf(vv[1]+1e-5f);
        rs[2] = __builtin_amdgcn_rsqf(vv[2]+1e-5f); rs[3] = __builtin_amdgcn_rsqf(vv[3]+1e-5f);
        f4 o = rs*(dt - mu*C1) + outc;
        if (nn == 0) *(f4*)(out + p0 + q*4) = o;
    }
}

extern "C" void kernel_launch(void* const* d_in, const int* in_sizes, int n_in,
                              void* d_out, int out_size, void* d_ws, size_t ws_size,
                              hipStream_t stream)
{
    const float* coords = (const float*)d_in[0];
    const float* cost   = (const float*)d_in[1];
    const float* lscale = (const float*)d_in[2];
    const float* W1     = (const float*)d_in[3];
    const float* b1     = (const float*)d_in[4];
    const float* W2     = (const float*)d_in[5];
    const float* b2     = (const float*)d_in[6];
    const float* fg     = (const float*)d_in[7];
    const float* fb     = (const float*)d_in[8];
    const float* Wg1    = (const float*)d_in[9];
    const float* bg1    = (const float*)d_in[10];
    const float* Wg2    = (const float*)d_in[11];
    const float* bg2    = (const float*)d_in[12];
    const float* gt     = (const float*)d_in[13];
    const float* lng    = (const float*)d_in[14];
    const float* lnb    = (const float*)d_in[15];
    const float* Wo     = (const float*)d_in[16];
    const float* bo     = (const float*)d_in[17];
    float* out = (float*)d_out;

    prep_kernel<<<8, 256, 0, stream>>>(W1, W2, Wg1, Wg2, lng, lnb, Wo);
    fused_kernel<<<BLOCKS, 256, 0, stream>>>(
        coords, cost, lscale, b1, b2, fg, fb, bg1, bg2, Wg2, gt, lng, Wo, bo, out);
}

// Round 12
// 168.394 us; speedup vs baseline: 1.0340x; 1.0340x over previous
//
#include <hip/hip_runtime.h>
#include <math.h>

typedef _Float16 h8 __attribute__((ext_vector_type(8)));
typedef _Float16 h4 __attribute__((ext_vector_type(4)));
typedef float    f4 __attribute__((ext_vector_type(4)));

#define NPAIR (8*256*256)
#define NTILE (NPAIR/16)          // 32768 tiles of 16 rows
#define BLOCKS 768                // 3 blocks/CU * 256 CUs: fully persistent grid
#define NWAVE (BLOCKS*4)          // 3072 waves, grid-stride over tiles

#define MFMA(a,b,c) __builtin_amdgcn_mfma_f32_16x16x32_f16((a),(b),(c),0,0,0)
// Compiler-order fence for the cross-lane LDS write->read stage chaining.
#define FENCE() asm volatile("" ::: "memory")

// Weight fragments (h8 units). k-indices of W2/Wg1 are PERMUTED to match the
// packed LDS layouts (reduction order over k is arbitrary as long as A and B
// agree):
//   h tile:  position p = (u%16)*4 + u/16        (u = hidden 0..63)
//   e tile:  position p = (u%16)*8 + (u/64)*4 + (u/16)%4   (u = 0..127)
// [0,256)    W1   [t*64+lane]   k 9..31 zero-padded (natural k order)
// [256,768)  W2   [c*256+t*64+lane]   k = k_h(32c+8q+j)
// [896,1920) Wg1  [c*256+t*64+lane]   k = k_e(32c+8q+j)
__device__ h8 g_all[1920];
__device__ float g_cc[2];         // C0 = sum ln_b*Wo, C1 = sum ln_g*Wo

__global__ void prep_kernel(const float* __restrict__ W1, const float* __restrict__ W2,
                            const float* __restrict__ Wg1, const float* __restrict__ Wg2,
                            const float* __restrict__ ln_g, const float* __restrict__ ln_b,
                            const float* __restrict__ Wo)
{
    int idx = blockIdx.x * 256 + threadIdx.x;
    if (idx < 256) {
        int t = idx >> 6, lane = idx & 63, q = lane >> 4, nn = lane & 15;
        h8 v;
#pragma unroll
        for (int j = 0; j < 8; ++j) { int k = 8*q + j; v[j] = (_Float16)((k < 9) ? W1[k*64 + 16*t + nn] : 0.f); }
        g_all[idx] = v;
    } else if (idx < 768) {
        int z = idx - 256; int c = z >> 8, t = (z >> 6) & 3, lane = z & 63, q = lane >> 4, nn = lane & 15;
        h8 v;
#pragma unroll
        for (int j = 0; j < 8; ++j) {
            int p = 32*c + 8*q + j;                 // position in packed h tile
            int k = (p >> 2) + 16*(p & 3);          // logical hidden index
            v[j] = (_Float16)W2[k*64 + 16*t + nn];
        }
        g_all[idx] = v;
    } else if (idx >= 896 && idx < 1920) {
        int z = idx - 896; int c = z >> 8, t = (z >> 6) & 3, lane = z & 63, q = lane >> 4, nn = lane & 15;
        h8 v;
#pragma unroll
        for (int j = 0; j < 8; ++j) {
            int p = 32*c + 8*q + j;                 // position in packed e tile
            int k = ((p >> 2) & 1)*64 + (p & 3)*16 + (p >> 3);
            v[j] = (_Float16)Wg1[k*64 + 16*t + nn];
        }
        g_all[idx] = v;
    } else if (idx == 1920) {
        float c0 = 0.f, c1 = 0.f;
        for (int k = 0; k < 64; ++k) { c0 += ln_b[k]*Wo[k]; c1 += ln_g[k]*Wo[k]; }
        g_cc[0] = c0; g_cc[1] = c1;
    }
}

__device__ __forceinline__ float sig(float x) { return __builtin_amdgcn_rcpf(1.f + __expf(-x)); }

__device__ __forceinline__ f4 silu4(f4 v)
{
    f4 r; r[0] = v[0]*sig(v[0]); r[1] = v[1]*sig(v[1]); r[2] = v[2]*sig(v[2]); r[3] = v[3]*sig(v[3]);
    return r;
}

// 16-lane reduction on the VALU pipe via DPP row_ror (rows of 16 = our groups).
template<int C>
__device__ __forceinline__ float rora(float x)
{
    int y = __builtin_amdgcn_update_dpp(0, __float_as_int(x), C, 0xF, 0xF, true);
    return x + __int_as_float(y);
}
__device__ __forceinline__ float red16s(float x)
{
    x = rora<0x121>(x);  // row_ror:1
    x = rora<0x122>(x);  // row_ror:2
    x = rora<0x124>(x);  // row_ror:4
    x = rora<0x128>(x);  // row_ror:8
    return x;
}
__device__ __forceinline__ f4 red16(f4 v)
{ v[0] = red16s(v[0]); v[1] = red16s(v[1]); v[2] = red16s(v[2]); v[3] = red16s(v[3]); return v; }

// R12: R11 (bounds-3, LDS weight pool, f32 fuse) with ~20 regs of peak-liveness
// trimmed to clear R11's residual spill (WRITE 33 MB -> target ~14 MB):
//   - gate1 sequential-K: one ae chunk (4 regs) live at a time, not 4 (16)
//   - L2 split by K-half: a00/a10 + v0..v3, then a01/a11 + v4..v7
//   - trig via double-angle: one sin+cos, 2x/4x/8x derived with fma/mul
// LDS: 28672 pool + 4*4608 = 47104 -> 3 blocks/CU = 3 waves/SIMD.
__global__ __launch_bounds__(256, 3) void fused_kernel(
    const float* __restrict__ coords, const float* __restrict__ cost,
    const float* __restrict__ lscale, const float* __restrict__ b1,
    const float* __restrict__ b2, const float* __restrict__ fgam,
    const float* __restrict__ fbet, const float* __restrict__ bg1,
    const float* __restrict__ bg2, const float* __restrict__ Wg2,
    const float* __restrict__ gt, const float* __restrict__ lng,
    const float* __restrict__ Wo, const float* __restrict__ bo,
    float* __restrict__ out)
{
    __shared__ __align__(16) char smem[28672 + 4*4608];
    const int tid = threadIdx.x;
    const int wave = tid >> 6, lane = tid & 63;
    const int q = lane >> 4, nn = lane & 15;

    h8* wp = (h8*)smem;                       // [0,1024) Wg1, [1024,1280) W1, [1280,1792) W2
    for (int z = tid; z < 1024; z += 256) wp[z] = g_all[896 + z];
    for (int z = tid; z < 768;  z += 256) wp[1024 + z] = g_all[z];
    __syncthreads();

    _Float16* U = (_Float16*)(smem + 28672 + wave*4608);  // aliased feat/h/e

    const float b1c0 = b1[nn], b1c1 = b1[16+nn], b1c2 = b1[32+nn], b1c3 = b1[48+nn];
    const float fg00 = fgam[nn], fg01 = fgam[16+nn], fg02 = fgam[32+nn], fg03 = fgam[48+nn];
    const float fg10 = fgam[64+nn], fg11 = fgam[80+nn], fg12 = fgam[96+nn], fg13 = fgam[112+nn];
    // FiLM beta with b2 folded in: e = acc*fg + (b2*fg + fb)
    const float fb00 = fmaf(b2[nn],    fg00, fbet[nn]);
    const float fb01 = fmaf(b2[16+nn], fg01, fbet[16+nn]);
    const float fb02 = fmaf(b2[32+nn], fg02, fbet[32+nn]);
    const float fb03 = fmaf(b2[48+nn], fg03, fbet[48+nn]);
    const float fb10 = fmaf(b2[nn],    fg10, fbet[64+nn]);
    const float fb11 = fmaf(b2[16+nn], fg11, fbet[80+nn]);
    const float fb12 = fmaf(b2[32+nn], fg12, fbet[96+nn]);
    const float fb13 = fmaf(b2[48+nn], fg13, fbet[112+nn]);
    const float bgc0 = bg1[nn], bgc1 = bg1[16+nn], bgc2 = bg1[32+nn], bgc3 = bg1[48+nn];
    const float gw0 = lng[nn]*Wo[nn], gw1 = lng[16+nn]*Wo[16+nn];
    const float gw2 = lng[32+nn]*Wo[32+nn], gw3 = lng[48+nn]*Wo[48+nn];
    const float wd0 = Wg2[nn*2+1]      - Wg2[nn*2];
    const float wd1 = Wg2[(16+nn)*2+1] - Wg2[(16+nn)*2];
    const float wd2 = Wg2[(32+nn)*2+1] - Wg2[(32+nn)*2];
    const float wd3 = Wg2[(48+nn)*2+1] - Wg2[(48+nn)*2];
    const float dlgb = bg2[1] - bg2[0];
    const float s0 = __expf(lscale[0]), s1 = __expf(lscale[1]);
    const float invT = __expf(-gt[0]);
    const float outc = g_cc[0] + bo[0], C1 = g_cc[1];

    for (int T = blockIdx.x*4 + wave; T < NTILE; T += NWAVE) {
        const int p0 = T*16;
        const int bb = p0 >> 16, ii = (p0 >> 8) & 255, j0 = p0 & 255;
        // ---- features: lanes 0-15 cost channel, 16-31 angle channel ----
        const float xc = cost[p0 + nn];
        const float* cb = coords + (bb << 9);
        const float xi = cb[2*ii], yi = cb[2*ii+1];
        const float xj = cb[2*(j0+nn)], yj = cb[2*(j0+nn)+1];
        const float ang = atan2f(yi - yj, xi - xj);
        const int isA = q & 1;
        const float xv = isA ? ang : xc;
        const float sE = isA ? s1 : s0;
        FENCE();                               // prior-iter LDS reads stay above
        if (lane < 32) {
            // trig via double-angle: one sin+cos, then 2x/4x/8x by recurrence
            const float sn1 = __sinf(xv), cs1 = __cosf(xv);
            const float sn2 = 2.f*sn1*cs1,  cs2 = fmaf(-2.f*sn1, sn1, 1.f);
            const float sn4 = 2.f*sn2*cs2,  cs4 = fmaf(-2.f*sn2, sn2, 1.f);
            const float sn8 = 2.f*sn4*cs4,  cs8 = fmaf(-2.f*sn4, sn4, 1.f);
            _Float16* fp = U + isA*640 + nn*40;
            h8 r0; r0[0]=(_Float16)(xv*sE);
            r0[1]=(_Float16)(sn1*sE); r0[2]=(_Float16)(cs1*sE);
            r0[3]=(_Float16)(sn2*sE); r0[4]=(_Float16)(cs2*sE);
            r0[5]=(_Float16)(sn4*sE); r0[6]=(_Float16)(cs4*sE);
            r0[7]=(_Float16)(sn8*sE);
            h8 rz = (h8)(_Float16)0.f;
            h8 r1 = rz; r1[0]=(_Float16)(cs8*sE);
            *(h8*)(fp)    = r0; *(h8*)(fp+8)  = r1;
            *(h8*)(fp+16) = rz; *(h8*)(fp+24) = rz;
        }
        FENCE();                               // feat writes before L1 reads
        // launder the LDS weight-pool index so per-iter reads can't be LICM'd
        int wofs = 0; asm volatile("" : "+s"(wofs));
        const h8* wpl = wp + wofs;
        // ---- L1: feats @ W1 -> silu -> packed h tile (pos = (u%16)*4+u/16) ----
        {
            h8 aF0 = *(h8*)(U + nn*40 + q*8);
            h8 aF1 = *(h8*)(U + 640 + nn*40 + q*8);
            h8 u0 = wpl[1024+lane], u1 = wpl[1088+lane], u2 = wpl[1152+lane], u3 = wpl[1216+lane];
            {
                f4 c0={b1c0,b1c0,b1c0,b1c0}, c1={b1c1,b1c1,b1c1,b1c1};
                f4 c2={b1c2,b1c2,b1c2,b1c2}, c3={b1c3,b1c3,b1c3,b1c3};
                c0=MFMA(aF0,u0,c0); c1=MFMA(aF0,u1,c1); c2=MFMA(aF0,u2,c2); c3=MFMA(aF0,u3,c3);
                c0=silu4(c0); c1=silu4(c1); c2=silu4(c2); c3=silu4(c3);
                _Float16* hb = U + (q*4)*72 + nn*4;
#pragma unroll
                for (int r = 0; r < 4; ++r) {
                    h4 pk; pk[0]=(_Float16)c0[r]; pk[1]=(_Float16)c1[r]; pk[2]=(_Float16)c2[r]; pk[3]=(_Float16)c3[r];
                    *(h4*)(hb + r*72) = pk;        // ds_write_b64
                }
            }
            {
                f4 c0={b1c0,b1c0,b1c0,b1c0}, c1={b1c1,b1c1,b1c1,b1c1};
                f4 c2={b1c2,b1c2,b1c2,b1c2}, c3={b1c3,b1c3,b1c3,b1c3};
                c0=MFMA(aF1,u0,c0); c1=MFMA(aF1,u1,c1); c2=MFMA(aF1,u2,c2); c3=MFMA(aF1,u3,c3);
                c0=silu4(c0); c1=silu4(c1); c2=silu4(c2); c3=silu4(c3);
                _Float16* hb = U + 1152 + (q*4)*72 + nn*4;
#pragma unroll
                for (int r = 0; r < 4; ++r) {
                    h4 pk; pk[0]=(_Float16)c0[r]; pk[1]=(_Float16)c1[r]; pk[2]=(_Float16)c2[r]; pk[3]=(_Float16)c3[r];
                    *(h4*)(hb + r*72) = pk;
                }
            }
        }
        FENCE();                               // h writes before L2 reads
        // ---- L2: h @ W2' (zero C-init; b2 in fb), K-halves sequential ----
        f4 E00,E01,E02,E03,E10,E11,E12,E13;
        {
            f4 z4 = {0.f,0.f,0.f,0.f};
            {   // K-half 0
                h8 a00 = *(h8*)(U + nn*72 + q*8);
                h8 a10 = *(h8*)(U + 1152 + nn*72 + q*8);
                h8 v0 = wpl[1280+lane], v1 = wpl[1344+lane], v2 = wpl[1408+lane], v3 = wpl[1472+lane];
                E00=MFMA(a00,v0,z4); E01=MFMA(a00,v1,z4); E02=MFMA(a00,v2,z4); E03=MFMA(a00,v3,z4);
                E10=MFMA(a10,v0,z4); E11=MFMA(a10,v1,z4); E12=MFMA(a10,v2,z4); E13=MFMA(a10,v3,z4);
            }
            {   // K-half 1
                h8 a01 = *(h8*)(U + nn*72 + 32 + q*8);
                h8 a11 = *(h8*)(U + 1152 + nn*72 + 32 + q*8);
                h8 v4 = wpl[1536+lane], v5 = wpl[1600+lane], v6 = wpl[1664+lane], v7 = wpl[1728+lane];
                E00=MFMA(a01,v4,E00); E01=MFMA(a01,v5,E01); E02=MFMA(a01,v6,E02); E03=MFMA(a01,v7,E03);
                E10=MFMA(a11,v4,E10); E11=MFMA(a11,v5,E11); E12=MFMA(a11,v6,E12); E13=MFMA(a11,v7,E13);
            }
            E00 = E00*fg00 + fb00; E01 = E01*fg01 + fb01; E02 = E02*fg02 + fb02; E03 = E03*fg03 + fb03;
            E10 = E10*fg10 + fb10; E11 = E11*fg11 + fb11; E12 = E12*fg12 + fb12; E13 = E13*fg13 + fb13;
            _Float16* eb = U + (q*4)*136 + nn*8;   // pos = (u%16)*8 + enc*4 + t
#pragma unroll
            for (int r = 0; r < 4; ++r) {
                h8 pk;
                pk[0]=(_Float16)E00[r]; pk[1]=(_Float16)E01[r]; pk[2]=(_Float16)E02[r]; pk[3]=(_Float16)E03[r];
                pk[4]=(_Float16)E10[r]; pk[5]=(_Float16)E11[r]; pk[6]=(_Float16)E12[r]; pk[7]=(_Float16)E13[r];
                *(h8*)(eb + r*136) = pk;           // ds_write_b128
            }
        }
        FENCE();                               // e writes before gate1 reads
        // ---- gate1: sequential-K (one ae chunk live at a time); gate2 in VALU ----
        f4 g0={bgc0,bgc0,bgc0,bgc0}, g1={bgc1,bgc1,bgc1,bgc1};
        f4 g2={bgc2,bgc2,bgc2,bgc2}, g3={bgc3,bgc3,bgc3,bgc3};
#pragma unroll
        for (int c = 0; c < 4; ++c) {
            h8 ae = *(h8*)(U + nn*136 + 32*c + q*8);
            g0 = MFMA(ae, wpl[c*256 +       lane], g0);
            g1 = MFMA(ae, wpl[c*256 +  64 + lane], g1);
            g2 = MFMA(ae, wpl[c*256 + 128 + lane], g2);
            g3 = MFMA(ae, wpl[c*256 + 192 + lane], g3);
        }
        g0=silu4(g0); g1=silu4(g1); g2=silu4(g2); g3=silu4(g3);
        // gate2 in VALU: per-row logit diff = red16 of per-lane partials
        f4 part = g0*wd0 + g1*wd1 + g2*wd2 + g3*wd3;
        f4 diff = red16(part);
        f4 w1v;
        w1v[0] = sig((diff[0]+dlgb)*invT); w1v[1] = sig((diff[1]+dlgb)*invT);
        w1v[2] = sig((diff[2]+dlgb)*invT); w1v[3] = sig((diff[3]+dlgb)*invT);
        // ---- fuse + LayerNorm + head from the f32 E-frags (R9 numerics) ----
        f4 fu0 = E00 + w1v*(E10-E00);
        f4 fu1 = E01 + w1v*(E11-E01);
        f4 fu2 = E02 + w1v*(E12-E02);
        f4 fu3 = E03 + w1v*(E13-E03);
        f4 sv = red16((fu0+fu1)+(fu2+fu3));
        f4 sq = red16((fu0*fu0+fu1*fu1)+(fu2*fu2+fu3*fu3));
        f4 dt = red16((fu0*gw0 + fu1*gw1) + (fu2*gw2 + fu3*gw3));
        f4 mu = sv * (1.f/64.f);
        f4 vv = sq * (1.f/64.f) - mu*mu;
        f4 rs;
        rs[0] = __builtin_amdgcn_rsqf(vv[0]+1e-5f); rs[1] = __builtin_amdgcn_rsqf(vv[1]+1e-5f);
        rs[2] = __builtin_amdgcn_rsqf(vv[2]+1e-5f); rs[3] = __builtin_amdgcn_rsqf(vv[3]+1e-5f);
        f4 o = rs*(dt - mu*C1) + outc;
        if (nn == 0) *(f4*)(out + p0 + q*4) = o;
    }
}

extern "C" void kernel_launch(void* const* d_in, const int* in_sizes, int n_in,
                              void* d_out, int out_size, void* d_ws, size_t ws_size,
                              hipStream_t stream)
{
    const float* coords = (const float*)d_in[0];
    const float* cost   = (const float*)d_in[1];
    const float* lscale = (const float*)d_in[2];
    const float* W1     = (const float*)d_in[3];
    const float* b1     = (const float*)d_in[4];
    const float* W2     = (const float*)d_in[5];
    const float* b2     = (const float*)d_in[6];
    const float* fg     = (const float*)d_in[7];
    const float* fb     = (const float*)d_in[8];
    const float* Wg1    = (const float*)d_in[9];
    const float* bg1    = (const float*)d_in[10];
    const float* Wg2    = (const float*)d_in[11];
    const float* bg2    = (const float*)d_in[12];
    const float* gt     = (const float*)d_in[13];
    const float* lng    = (const float*)d_in[14];
    const float* lnb    = (const float*)d_in[15];
    const float* Wo     = (const float*)d_in[16];
    const float* bo     = (const float*)d_in[17];
    float* out = (float*)d_out;

    prep_kernel<<<8, 256, 0, stream>>>(W1, W2, Wg1, Wg2, lng, lnb, Wo);
    fused_kernel<<<BLOCKS, 256, 0, stream>>>(
        coords, cost, lscale, b1, b2, fg, fb, bg1, bg2, Wg2, gt, lng, Wo, bo, out);
}

// Round 14
// 156.258 us; speedup vs baseline: 1.1143x; 1.0777x over previous
//
#include <hip/hip_runtime.h>
#include <math.h>

typedef _Float16 h4 __attribute__((ext_vector_type(4)));
typedef __fp16   p2 __attribute__((ext_vector_type(2)));   // cvt_pkrtz result type
typedef float    f4 __attribute__((ext_vector_type(4)));

#define NPAIR (8*256*256)
#define NTILE (NPAIR/16)          // 32768 tiles of 16 pairs
#define BLOCKS 2048
#define ITERS (NTILE/(BLOCKS*4))  // 4 tiles per wave

// 16x16x16 f16 MFMA: C/D layout (row=4q+reg, col=lane&15) == B layout
// (k=4q+j, n=lane&15)  ->  layers chain in-register via per-lane cvt only.
#define MFMA16(a,b,c) __builtin_amdgcn_mfma_f32_16x16x16f16((a),(b),(c),0,0,0)
#define FENCE() asm volatile("" ::: "memory")

// A-fragment pool (h4 units, transposed weights: m=out-channel on lane&15,
// k=in-channel = 4q+j):
// [0,256)     W1^T  [t*64+lane]                 k<9 -> W1[k][16t+nn]; k==9 -> b1; else 0
// [256,2304)  W2'^T [((enc*4+ct)*4+kc)*64+lane] W2[16kc+4q+j][16ct+nn] * fg_enc[16ct+nn]
// [2304,4352) Wg1^T [(vt*8+kc)*64+lane]         Wg1[16kc+4q+j][16vt+nn]
__device__ h4 g_all[4352];
__device__ float g_cc[2];         // C0 = sum ln_b*Wo, C1 = sum ln_g*Wo

__global__ void prep_kernel(const float* __restrict__ W1, const float* __restrict__ b1,
                            const float* __restrict__ W2, const float* __restrict__ fgam,
                            const float* __restrict__ Wg1,
                            const float* __restrict__ ln_g, const float* __restrict__ ln_b,
                            const float* __restrict__ Wo)
{
    int idx = blockIdx.x * 256 + threadIdx.x;
    int lane = idx & 63, q = (lane >> 4), nn = lane & 15;
    if (idx < 256) {
        int t = idx >> 6;
        h4 v;
#pragma unroll
        for (int j = 0; j < 4; ++j) {
            int k = 4*q + j;
            float x = (k < 9) ? W1[k*64 + 16*t + nn] : (k == 9 ? b1[16*t + nn] : 0.f);
            v[j] = (_Float16)x;
        }
        g_all[idx] = v;
    } else if (idx < 2304) {
        int z = idx - 256; int g = z >> 6;          // g = (enc*4+ct)*4+kc
        int kc = g & 3, ct = (g >> 2) & 3, enc = g >> 4;
        h4 v;
#pragma unroll
        for (int j = 0; j < 4; ++j) {
            int k = 16*kc + 4*q + j, c = 16*ct + nn;
            v[j] = (_Float16)(W2[k*64 + c] * fgam[enc*64 + c]);
        }
        g_all[idx] = v;
    } else if (idx < 4352) {
        int z = idx - 2304; int g = z >> 6;         // g = vt*8+kc
        int kc = g & 7, vt = g >> 3;
        h4 v;
#pragma unroll
        for (int j = 0; j < 4; ++j) {
            int k = 16*kc + 4*q + j;
            v[j] = (_Float16)Wg1[k*64 + 16*vt + nn];
        }
        g_all[idx] = v;
    } else if (idx == 4352) {
        float c0 = 0.f, c1 = 0.f;
        for (int k = 0; k < 64; ++k) { c0 += ln_b[k]*Wo[k]; c1 += ln_g[k]*Wo[k]; }
        g_cc[0] = c0; g_cc[1] = c1;
    }
}

__device__ __forceinline__ float sig(float x) { return __builtin_amdgcn_rcpf(1.f + __expf(-x)); }

__device__ __forceinline__ f4 silu4(f4 v)
{
    f4 r; r[0] = v[0]*sig(v[0]); r[1] = v[1]*sig(v[1]); r[2] = v[2]*sig(v[2]); r[3] = v[3]*sig(v[3]);
    return r;
}

__device__ __forceinline__ h4 pk4(f4 v)   // f32x4 -> f16x4, 2x v_cvt_pkrtz
{
    p2 lo = __builtin_amdgcn_cvt_pkrtz(v[0], v[1]);
    p2 hi = __builtin_amdgcn_cvt_pkrtz(v[2], v[3]);
    h4 r; r[0] = (_Float16)lo[0]; r[1] = (_Float16)lo[1];
          r[2] = (_Float16)hi[0]; r[3] = (_Float16)hi[1];
    return r;
}

// per-lane constant loader: channel c = 16t + 4q + r for this lane's q
#define MKCONST(t) \
    f4 b2a##t, b2b##t, bgc##t, wdl##t, gwl##t; \
    { _Pragma("unroll") \
      for (int r = 0; r < 4; ++r) { \
        int c = 16*t + q4 + r; \
        b2a##t[r] = fmaf(b2[c], fgam[c],      fbet[c]); \
        b2b##t[r] = fmaf(b2[c], fgam[64 + c], fbet[64 + c]); \
        bgc##t[r] = bg1[c]; \
        wdl##t[r] = Wg2[2*c + 1] - Wg2[2*c]; \
        gwl##t[r] = lng[c] * Wo[c]; \
      } }

// LDS: 32 KB weight pool (W2' + Wg1 A-frags, streamed per iter) + 4 waves *
// 1280 B feature tile. All layer transitions are IN-REGISTER (C/D->B chain);
// the only LDS dependency hop is the feature tile. bounds(256,2): R4-R12
// showed this kernel's spill-free point; DS chain is gone so latency
// tolerance at 2 waves/SIMD is no longer the limiter.
__global__ __launch_bounds__(256, 2) void fused_kernel(
    const float* __restrict__ coords, const float* __restrict__ cost,
    const float* __restrict__ lscale, const float* __restrict__ b2,
    const float* __restrict__ fgam, const float* __restrict__ fbet,
    const float* __restrict__ bg1, const float* __restrict__ bg2,
    const float* __restrict__ Wg2, const float* __restrict__ gt,
    const float* __restrict__ lng, const float* __restrict__ Wo,
    const float* __restrict__ bo, float* __restrict__ out)
{
    __shared__ __align__(16) char smem[32768 + 4*1280];
    const int tid = threadIdx.x;
    const int wave = tid >> 6, lane = tid & 63;
    const int q = lane >> 4, nn = lane & 15;
    const int q4 = q*4;

    h4* wpool = (h4*)smem;                    // [0,2048) W2', [2048,4096) Wg1
    for (int z = tid; z < 4096; z += 256) wpool[z] = g_all[256 + z];
    __syncthreads();

    _Float16* U = (_Float16*)(smem + 32768 + wave*1280);  // feat: [enc][16 pairs][20]
    for (int z = lane; z < 320; z += 64) ((float*)U)[z] = 0.f;  // zero pads once

    // W1^T A-frags, register-resident (8 VGPRs)
    h4 w1a0 = g_all[lane], w1a1 = g_all[64+lane], w1a2 = g_all[128+lane], w1a3 = g_all[192+lane];

    MKCONST(0) MKCONST(1) MKCONST(2) MKCONST(3)

    const float dlgb = bg2[1] - bg2[0];
    const float s0 = __expf(lscale[0]), s1 = __expf(lscale[1]);
    const float invT = __expf(-gt[0]);
    const float outc = g_cc[0] + bo[0], C1 = g_cc[1];

    const int wgid = blockIdx.x*4 + wave;

    for (int it = 0; it < ITERS; ++it) {
        const int T = wgid + it*(BLOCKS*4);
        const int p0 = T*16;
        const int bb = p0 >> 16, ii = (p0 >> 8) & 255, j0 = p0 & 255;
        // ---- features: lanes 0-15 cost enc, 16-31 angle enc; 1 LDS hop ----
        const float xc = cost[p0 + nn];
        const float* cb = coords + (bb << 9);
        const float xi = cb[2*ii], yi = cb[2*ii+1];
        const float xj = cb[2*(j0+nn)], yj = cb[2*(j0+nn)+1];
        const float ang = atan2f(yi - yj, xi - xj);
        const int isA = q & 1;
        const float xv = isA ? ang : xc;
        const float sE = isA ? s1 : s0;
        FENCE();
        if (lane < 32) {
            const float sn1 = __sinf(xv), cs1 = __cosf(xv);
            const float sn2 = 2.f*sn1*cs1, cs2 = fmaf(-2.f*sn1, sn1, 1.f);
            const float sn4 = 2.f*sn2*cs2, cs4 = fmaf(-2.f*sn2, sn2, 1.f);
            const float sn8 = 2.f*sn4*cs4, cs8 = fmaf(-2.f*sn4, sn4, 1.f);
            _Float16* fp = U + isA*320 + nn*20;
            p2 p01 = __builtin_amdgcn_cvt_pkrtz(xv*sE,  sn1*sE);
            p2 p23 = __builtin_amdgcn_cvt_pkrtz(cs1*sE, sn2*sE);
            p2 p45 = __builtin_amdgcn_cvt_pkrtz(cs2*sE, sn4*sE);
            p2 p67 = __builtin_amdgcn_cvt_pkrtz(cs4*sE, sn8*sE);
            p2 p89 = __builtin_amdgcn_cvt_pkrtz(cs8*sE, 1.0f);  // k=9: homogeneous 1 (W1 row 9 = b1)
            h4 w0; w0[0]=(_Float16)p01[0]; w0[1]=(_Float16)p01[1];
                   w0[2]=(_Float16)p23[0]; w0[3]=(_Float16)p23[1];
            h4 w1; w1[0]=(_Float16)p45[0]; w1[1]=(_Float16)p45[1];
                   w1[2]=(_Float16)p67[0]; w1[3]=(_Float16)p67[1];
            *(h4*)(fp)     = w0;   // ds_write_b64
            *(h4*)(fp + 4) = w1;
            fp[8] = (_Float16)p89[0];   // cs8 term
            fp[9] = (_Float16)p89[1];   // homogeneous 1 -> W1 row 9 (= b1)
        }
        FENCE();
        // ---- L1: h^T = W1^T @ feat^T (K=16 covers 9 feats + bias-1) ----
        h4 fB0 = *(h4*)(U + nn*20 + q4);
        h4 fB1 = *(h4*)(U + 320 + nn*20 + q4);
        const f4 z4 = {0.f, 0.f, 0.f, 0.f};
        f4 H00 = MFMA16(w1a0, fB0, z4), H01 = MFMA16(w1a1, fB0, z4);
        f4 H02 = MFMA16(w1a2, fB0, z4), H03 = MFMA16(w1a3, fB0, z4);
        f4 H10 = MFMA16(w1a0, fB1, z4), H11 = MFMA16(w1a1, fB1, z4);
        f4 H12 = MFMA16(w1a2, fB1, z4), H13 = MFMA16(w1a3, fB1, z4);
        // silu -> f16 B-frags for L2 (pure per-lane cvt, no LDS)
        h4 hB00 = pk4(silu4(H00)), hB01 = pk4(silu4(H01)), hB02 = pk4(silu4(H02)), hB03 = pk4(silu4(H03));
        h4 hB10 = pk4(silu4(H10)), hB11 = pk4(silu4(H11)), hB12 = pk4(silu4(H12)), hB13 = pk4(silu4(H13));
        // launder pool index: block LICM from hoisting 64 weight frags to regs
        int wofs = 0; asm volatile("" : "+s"(wofs));
        const h4* wpl = wpool + wofs;
        // ---- L2: e^T = W2'^T @ h^T + b2' (FiLM folded; C-init = per-lane b2') ----
        f4 E00 = b2a0, E01 = b2a1, E02 = b2a2, E03 = b2a3;   // enc0, c-tiles 0..3
        f4 E10 = b2b0, E11 = b2b1, E12 = b2b2, E13 = b2b3;   // enc1
        E00=MFMA16(wpl[ 0*64+lane],hB00,E00); E00=MFMA16(wpl[ 1*64+lane],hB01,E00); E00=MFMA16(wpl[ 2*64+lane],hB02,E00); E00=MFMA16(wpl[ 3*64+lane],hB03,E00);
        E01=MFMA16(wpl[ 4*64+lane],hB00,E01); E01=MFMA16(wpl[ 5*64+lane],hB01,E01); E01=MFMA16(wpl[ 6*64+lane],hB02,E01); E01=MFMA16(wpl[ 7*64+lane],hB03,E01);
        E02=MFMA16(wpl[ 8*64+lane],hB00,E02); E02=MFMA16(wpl[ 9*64+lane],hB01,E02); E02=MFMA16(wpl[10*64+lane],hB02,E02); E02=MFMA16(wpl[11*64+lane],hB03,E02);
        E03=MFMA16(wpl[12*64+lane],hB00,E03); E03=MFMA16(wpl[13*64+lane],hB01,E03); E03=MFMA16(wpl[14*64+lane],hB02,E03); E03=MFMA16(wpl[15*64+lane],hB03,E03);
        E10=MFMA16(wpl[16*64+lane],hB10,E10); E10=MFMA16(wpl[17*64+lane],hB11,E10); E10=MFMA16(wpl[18*64+lane],hB12,E10); E10=MFMA16(wpl[19*64+lane],hB13,E10);
        E11=MFMA16(wpl[20*64+lane],hB10,E11); E11=MFMA16(wpl[21*64+lane],hB11,E11); E11=MFMA16(wpl[22*64+lane],hB12,E11); E11=MFMA16(wpl[23*64+lane],hB13,E11);
        E12=MFMA16(wpl[24*64+lane],hB10,E12); E12=MFMA16(wpl[25*64+lane],hB11,E12); E12=MFMA16(wpl[26*64+lane],hB12,E12); E12=MFMA16(wpl[27*64+lane],hB13,E12);
        E13=MFMA16(wpl[28*64+lane],hB10,E13); E13=MFMA16(wpl[29*64+lane],hB11,E13); E13=MFMA16(wpl[30*64+lane],hB12,E13); E13=MFMA16(wpl[31*64+lane],hB13,E13);
        // e -> f16 B-frags for gate1 (per-lane cvt); f32 E kept for fuse/LN
        h4 eB0 = pk4(E00), eB1 = pk4(E01), eB2 = pk4(E02), eB3 = pk4(E03);
        h4 eB4 = pk4(E10), eB5 = pk4(E11), eB6 = pk4(E12), eB7 = pk4(E13);
        // ---- gate1: g^T = Wg1^T @ [e0|e1]^T + bg1 (K=128 = 8 chunks) ----
        f4 G0 = bgc0, G1 = bgc1, G2 = bgc2, G3 = bgc3;
        G0=MFMA16(wpl[2048+ 0*64+lane],eB0,G0); G0=MFMA16(wpl[2048+ 1*64+lane],eB1,G0);
        G0=MFMA16(wpl[2048+ 2*64+lane],eB2,G0); G0=MFMA16(wpl[2048+ 3*64+lane],eB3,G0);
        G0=MFMA16(wpl[2048+ 4*64+lane],eB4,G0); G0=MFMA16(wpl[2048+ 5*64+lane],eB5,G0);
        G0=MFMA16(wpl[2048+ 6*64+lane],eB6,G0); G0=MFMA16(wpl[2048+ 7*64+lane],eB7,G0);
        G1=MFMA16(wpl[2048+ 8*64+lane],eB0,G1); G1=MFMA16(wpl[2048+ 9*64+lane],eB1,G1);
        G1=MFMA16(wpl[2048+10*64+lane],eB2,G1); G1=MFMA16(wpl[2048+11*64+lane],eB3,G1);
        G1=MFMA16(wpl[2048+12*64+lane],eB4,G1); G1=MFMA16(wpl[2048+13*64+lane],eB5,G1);
        G1=MFMA16(wpl[2048+14*64+lane],eB6,G1); G1=MFMA16(wpl[2048+15*64+lane],eB7,G1);
        G2=MFMA16(wpl[2048+16*64+lane],eB0,G2); G2=MFMA16(wpl[2048+17*64+lane],eB1,G2);
        G2=MFMA16(wpl[2048+18*64+lane],eB2,G2); G2=MFMA16(wpl[2048+19*64+lane],eB3,G2);
        G2=MFMA16(wpl[2048+20*64+lane],eB4,G2); G2=MFMA16(wpl[2048+21*64+lane],eB5,G2);
        G2=MFMA16(wpl[2048+22*64+lane],eB6,G2); G2=MFMA16(wpl[2048+23*64+lane],eB7,G2);
        G3=MFMA16(wpl[2048+24*64+lane],eB0,G3); G3=MFMA16(wpl[2048+25*64+lane],eB1,G3);
        G3=MFMA16(wpl[2048+26*64+lane],eB2,G3); G3=MFMA16(wpl[2048+27*64+lane],eB3,G3);
        G3=MFMA16(wpl[2048+28*64+lane],eB4,G3); G3=MFMA16(wpl[2048+29*64+lane],eB5,G3);
        G3=MFMA16(wpl[2048+30*64+lane],eB6,G3); G3=MFMA16(wpl[2048+31*64+lane],eB7,G3);
        G0 = silu4(G0); G1 = silu4(G1); G2 = silu4(G2); G3 = silu4(G3);
        // ---- gate2 (VALU): logit diff = sum_v g[v]*wd[v], cross-quad via shfl ----
        float part = G0[0]*wdl0[0];
        part = fmaf(G0[1], wdl0[1], part); part = fmaf(G0[2], wdl0[2], part); part = fmaf(G0[3], wdl0[3], part);
        part = fmaf(G1[0], wdl1[0], part); part = fmaf(G1[1], wdl1[1], part); part = fmaf(G1[2], wdl1[2], part); part = fmaf(G1[3], wdl1[3], part);
        part = fmaf(G2[0], wdl2[0], part); part = fmaf(G2[1], wdl2[1], part); part = fmaf(G2[2], wdl2[2], part); part = fmaf(G2[3], wdl2[3], part);
        part = fmaf(G3[0], wdl3[0], part); part = fmaf(G3[1], wdl3[1], part); part = fmaf(G3[2], wdl3[2], part); part = fmaf(G3[3], wdl3[3], part);
        part += __shfl_xor(part, 16); part += __shfl_xor(part, 32);
        const float w1 = sig((part + dlgb)*invT);
        // ---- fuse + LayerNorm + head (f32, per-lane partials + 2 shfl each) ----
        f4 fu0 = E00 + w1*(E10-E00);
        f4 fu1 = E01 + w1*(E11-E01);
        f4 fu2 = E02 + w1*(E12-E02);
        f4 fu3 = E03 + w1*(E13-E03);
        f4 sfv = (fu0+fu1)+(fu2+fu3);
        float sv = (sfv[0]+sfv[1])+(sfv[2]+sfv[3]);
        f4 sfq = (fu0*fu0+fu1*fu1)+(fu2*fu2+fu3*fu3);
        float sq = (sfq[0]+sfq[1])+(sfq[2]+sfq[3]);
        f4 sfd = (fu0*gwl0+fu1*gwl1)+(fu2*gwl2+fu3*gwl3);
        float dt = (sfd[0]+sfd[1])+(sfd[2]+sfd[3]);
        sv += __shfl_xor(sv, 16); sv += __shfl_xor(sv, 32);
        sq += __shfl_xor(sq, 16); sq += __shfl_xor(sq, 32);
        dt += __shfl_xor(dt, 16); dt += __shfl_xor(dt, 32);
        const float mu = sv * (1.f/64.f);
        const float vv = sq * (1.f/64.f) - mu*mu;
        const float rs = __builtin_amdgcn_rsqf(vv + 1e-5f);
        const float o = fmaf(rs, dt - mu*C1, outc);
        if (lane < 16) out[p0 + lane] = o;
    }
}

extern "C" void kernel_launch(void* const* d_in, const int* in_sizes, int n_in,
                              void* d_out, int out_size, void* d_ws, size_t ws_size,
                              hipStream_t stream)
{
    const float* coords = (const float*)d_in[0];
    const float* cost   = (const float*)d_in[1];
    const float* lscale = (const float*)d_in[2];
    const float* W1     = (const float*)d_in[3];
    const float* b1     = (const float*)d_in[4];
    const float* W2     = (const float*)d_in[5];
    const float* b2     = (const float*)d_in[6];
    const float* fg     = (const float*)d_in[7];
    const float* fb     = (const float*)d_in[8];
    const float* Wg1    = (const float*)d_in[9];
    const float* bg1    = (const float*)d_in[10];
    const float* Wg2    = (const float*)d_in[11];
    const float* bg2    = (const float*)d_in[12];
    const float* gt     = (const float*)d_in[13];
    const float* lng    = (const float*)d_in[14];
    const float* lnb    = (const float*)d_in[15];
    const float* Wo     = (const float*)d_in[16];
    const float* bo     = (const float*)d_in[17];
    float* out = (float*)d_out;

    prep_kernel<<<18, 256, 0, stream>>>(W1, b1, W2, fg, Wg1, lng, lnb, Wo);
    fused_kernel<<<BLOCKS, 256, 0, stream>>>(
        coords, cost, lscale, b2, fg, fb, bg1, bg2, Wg2, gt, lng, Wo, bo, out);
}

// Round 15
// 137.114 us; speedup vs baseline: 1.2699x; 1.1396x over previous
//
#include <hip/hip_runtime.h>
#include <math.h>

typedef _Float16 h4 __attribute__((ext_vector_type(4)));
typedef __fp16   p2 __attribute__((ext_vector_type(2)));   // cvt_pkrtz result type
typedef float    f4 __attribute__((ext_vector_type(4)));

#define NPAIR (8*256*256)
#define NTILE (NPAIR/16)          // 32768 tiles of 16 pairs
#define BLOCKS 2048
#define ITERS (NTILE/(BLOCKS*4))  // 4 tiles per wave

// 16x16x16 f16 MFMA: C/D layout (row=4q+reg, col=lane&15) == B layout
// (k=4q+j, n=lane&15)  ->  layers chain in-register via per-lane cvt only.
#define MFMA16(a,b,c) __builtin_amdgcn_mfma_f32_16x16x16f16((a),(b),(c),0,0,0)
#define FENCE() asm volatile("" ::: "memory")

// A-fragment pool (h4 units, transposed weights: m=out-channel on lane&15,
// k=in-channel = 4q+j):
// [0,256)     W1^T  [t*64+lane]                 k<9 -> W1[k][16t+nn]; k==9 -> b1; else 0
// [256,2304)  W2'^T [((enc*4+ct)*4+kc)*64+lane] W2[16kc+4q+j][16ct+nn] * fg_enc[16ct+nn]
// [2304,4352) Wg1^T [(vt*8+kc)*64+lane]         Wg1[16kc+4q+j][16vt+nn]
__device__ h4 g_all[4352];
// Per-channel epilogue constants (c = 0..63):
// [0,64) b2*fg0+fb0  [64,128) b2*fg1+fb1  [128,192) bg1
// [192,256) Wg2[c][1]-Wg2[c][0]  [256,320) ln_g*Wo
__device__ float g_cst[320];
__device__ float g_cc[2];         // C0 = sum ln_b*Wo, C1 = sum ln_g*Wo

__global__ void prep_kernel(const float* __restrict__ W1, const float* __restrict__ b1,
                            const float* __restrict__ W2, const float* __restrict__ b2,
                            const float* __restrict__ fgam, const float* __restrict__ fbet,
                            const float* __restrict__ Wg1, const float* __restrict__ bg1,
                            const float* __restrict__ Wg2,
                            const float* __restrict__ ln_g, const float* __restrict__ ln_b,
                            const float* __restrict__ Wo)
{
    int idx = blockIdx.x * 256 + threadIdx.x;
    int lane = idx & 63, q = (lane >> 4), nn = lane & 15;
    if (idx < 256) {
        int t = idx >> 6;
        h4 v;
#pragma unroll
        for (int j = 0; j < 4; ++j) {
            int k = 4*q + j;
            float x = (k < 9) ? W1[k*64 + 16*t + nn] : (k == 9 ? b1[16*t + nn] : 0.f);
            v[j] = (_Float16)x;
        }
        g_all[idx] = v;
    } else if (idx < 2304) {
        int z = idx - 256; int g = z >> 6;          // g = (enc*4+ct)*4+kc
        int kc = g & 3, ct = (g >> 2) & 3, enc = g >> 4;
        h4 v;
#pragma unroll
        for (int j = 0; j < 4; ++j) {
            int k = 16*kc + 4*q + j, c = 16*ct + nn;
            v[j] = (_Float16)(W2[k*64 + c] * fgam[enc*64 + c]);
        }
        g_all[idx] = v;
    } else if (idx < 4352) {
        int z = idx - 2304; int g = z >> 6;         // g = vt*8+kc
        int kc = g & 7, vt = g >> 3;
        h4 v;
#pragma unroll
        for (int j = 0; j < 4; ++j) {
            int k = 16*kc + 4*q + j;
            v[j] = (_Float16)Wg1[k*64 + 16*vt + nn];
        }
        g_all[idx] = v;
    } else if (idx == 4352) {
        float c0 = 0.f, c1 = 0.f;
        for (int k = 0; k < 64; ++k) { c0 += ln_b[k]*Wo[k]; c1 += ln_g[k]*Wo[k]; }
        g_cc[0] = c0; g_cc[1] = c1;
    } else if (idx >= 4608 && idx < 4928) {
        int c = idx - 4608;
        float v;
        if (c < 64)        v = fmaf(b2[c], fgam[c], fbet[c]);
        else if (c < 128)  { int cc = c-64;  v = fmaf(b2[cc], fgam[64+cc], fbet[64+cc]); }
        else if (c < 192)  v = bg1[c-128];
        else if (c < 256)  { int cc = c-192; v = Wg2[2*cc+1] - Wg2[2*cc]; }
        else               { int cc = c-256; v = ln_g[cc]*Wo[cc]; }
        g_cst[c] = v;
    }
}

__device__ __forceinline__ float sig(float x) { return __builtin_amdgcn_rcpf(1.f + __expf(-x)); }

__device__ __forceinline__ f4 silu4(f4 v)
{
    f4 r; r[0] = v[0]*sig(v[0]); r[1] = v[1]*sig(v[1]); r[2] = v[2]*sig(v[2]); r[3] = v[3]*sig(v[3]);
    return r;
}

__device__ __forceinline__ h4 pk4(f4 v)   // f32x4 -> f16x4, 2x v_cvt_pkrtz
{
    p2 lo = __builtin_amdgcn_cvt_pkrtz(v[0], v[1]);
    p2 hi = __builtin_amdgcn_cvt_pkrtz(v[2], v[3]);
    h4 r; r[0] = (_Float16)lo[0]; r[1] = (_Float16)lo[1];
          r[2] = (_Float16)hi[0]; r[3] = (_Float16)hi[1];
    return r;
}

// R15 = R14 + per-lane epilogue constants moved from 80 persistent VGPRs into
// the block LDS pool (re-read per iter via laundered pointer: 20 ds_read_b128,
// issued at use). Persistent reg state drops to ~30; peak total ~150 < 168,
// so bounds(256,3) should hold spill-free -> 3 waves/SIMD (R14: 2, stall 34%).
// LDS: 32768 wpool + 1280 cst + 4*1280 feat = 39168 -> 4 blocks/CU by LDS.
__global__ __launch_bounds__(256, 3) void fused_kernel(
    const float* __restrict__ coords, const float* __restrict__ cost,
    const float* __restrict__ lscale, const float* __restrict__ bg2,
    const float* __restrict__ gt, const float* __restrict__ bo,
    float* __restrict__ out)
{
    __shared__ __align__(16) char smem[32768 + 1280 + 4*1280];
    const int tid = threadIdx.x;
    const int wave = tid >> 6, lane = tid & 63;
    const int q = lane >> 4, nn = lane & 15;
    const int q4 = q*4;

    h4* wpool = (h4*)smem;                    // [0,2048) W2', [2048,4096) Wg1
    for (int z = tid; z < 4096; z += 256) wpool[z] = g_all[256 + z];
    float* cpool = (float*)(smem + 32768);    // 320 epilogue consts
    for (int z = tid; z < 320; z += 256) cpool[z] = g_cst[z];
    __syncthreads();

    _Float16* U = (_Float16*)(smem + 34048 + wave*1280);  // feat: [enc][16 pairs][20]
    for (int z = lane; z < 320; z += 64) ((float*)U)[z] = 0.f;  // zero pads once

    // W1^T A-frags, register-resident (8 VGPRs)
    h4 w1a0 = g_all[lane], w1a1 = g_all[64+lane], w1a2 = g_all[128+lane], w1a3 = g_all[192+lane];

    const float dlgb = bg2[1] - bg2[0];
    const float s0 = __expf(lscale[0]), s1 = __expf(lscale[1]);
    const float invT = __expf(-gt[0]);
    const float outc = g_cc[0] + bo[0], C1 = g_cc[1];

    const int wgid = blockIdx.x*4 + wave;

    for (int it = 0; it < ITERS; ++it) {
        const int T = wgid + it*(BLOCKS*4);
        const int p0 = T*16;
        const int bb = p0 >> 16, ii = (p0 >> 8) & 255, j0 = p0 & 255;
        // ---- features: lanes 0-15 cost enc, 16-31 angle enc; 1 LDS hop ----
        const float xc = cost[p0 + nn];
        const float* cb = coords + (bb << 9);
        const float xi = cb[2*ii], yi = cb[2*ii+1];
        const float xj = cb[2*(j0+nn)], yj = cb[2*(j0+nn)+1];
        const float ang = atan2f(yi - yj, xi - xj);
        const int isA = q & 1;
        const float xv = isA ? ang : xc;
        const float sE = isA ? s1 : s0;
        FENCE();
        if (lane < 32) {
            const float sn1 = __sinf(xv), cs1 = __cosf(xv);
            const float sn2 = 2.f*sn1*cs1, cs2 = fmaf(-2.f*sn1, sn1, 1.f);
            const float sn4 = 2.f*sn2*cs2, cs4 = fmaf(-2.f*sn2, sn2, 1.f);
            const float sn8 = 2.f*sn4*cs4, cs8 = fmaf(-2.f*sn4, sn4, 1.f);
            _Float16* fp = U + isA*320 + nn*20;
            p2 p01 = __builtin_amdgcn_cvt_pkrtz(xv*sE,  sn1*sE);
            p2 p23 = __builtin_amdgcn_cvt_pkrtz(cs1*sE, sn2*sE);
            p2 p45 = __builtin_amdgcn_cvt_pkrtz(cs2*sE, sn4*sE);
            p2 p67 = __builtin_amdgcn_cvt_pkrtz(cs4*sE, sn8*sE);
            p2 p89 = __builtin_amdgcn_cvt_pkrtz(cs8*sE, 1.0f);  // k=9: homogeneous 1 (W1 row 9 = b1)
            h4 w0; w0[0]=(_Float16)p01[0]; w0[1]=(_Float16)p01[1];
                   w0[2]=(_Float16)p23[0]; w0[3]=(_Float16)p23[1];
            h4 w1; w1[0]=(_Float16)p45[0]; w1[1]=(_Float16)p45[1];
                   w1[2]=(_Float16)p67[0]; w1[3]=(_Float16)p67[1];
            *(h4*)(fp)     = w0;   // ds_write_b64
            *(h4*)(fp + 4) = w1;
            fp[8] = (_Float16)p89[0];   // cs8 term
            fp[9] = (_Float16)p89[1];   // homogeneous 1 -> W1 row 9 (= b1)
        }
        FENCE();
        // ---- L1: h^T = W1^T @ feat^T (K=16 covers 9 feats + bias-1) ----
        h4 fB0 = *(h4*)(U + nn*20 + q4);
        h4 fB1 = *(h4*)(U + 320 + nn*20 + q4);
        const f4 z4 = {0.f, 0.f, 0.f, 0.f};
        f4 H00 = MFMA16(w1a0, fB0, z4), H01 = MFMA16(w1a1, fB0, z4);
        f4 H02 = MFMA16(w1a2, fB0, z4), H03 = MFMA16(w1a3, fB0, z4);
        f4 H10 = MFMA16(w1a0, fB1, z4), H11 = MFMA16(w1a1, fB1, z4);
        f4 H12 = MFMA16(w1a2, fB1, z4), H13 = MFMA16(w1a3, fB1, z4);
        // silu -> f16 B-frags for L2 (pure per-lane cvt, no LDS)
        h4 hB00 = pk4(silu4(H00)), hB01 = pk4(silu4(H01)), hB02 = pk4(silu4(H02)), hB03 = pk4(silu4(H03));
        h4 hB10 = pk4(silu4(H10)), hB11 = pk4(silu4(H11)), hB12 = pk4(silu4(H12)), hB13 = pk4(silu4(H13));
        // launder pool index: block LICM from hoisting weight frags / consts to regs
        int wofs = 0; asm volatile("" : "+s"(wofs));
        const h4* wpl = wpool + wofs;
        const float* cstl = cpool + wofs;
        // ---- L2: e^T = W2'^T @ h^T + b2' (FiLM folded; C-init from LDS consts) ----
        f4 E00 = *(f4*)(cstl + q4),       E01 = *(f4*)(cstl + 16 + q4);
        f4 E02 = *(f4*)(cstl + 32 + q4),  E03 = *(f4*)(cstl + 48 + q4);
        f4 E10 = *(f4*)(cstl + 64 + q4),  E11 = *(f4*)(cstl + 80 + q4);
        f4 E12 = *(f4*)(cstl + 96 + q4),  E13 = *(f4*)(cstl + 112 + q4);
        E00=MFMA16(wpl[ 0*64+lane],hB00,E00); E00=MFMA16(wpl[ 1*64+lane],hB01,E00); E00=MFMA16(wpl[ 2*64+lane],hB02,E00); E00=MFMA16(wpl[ 3*64+lane],hB03,E00);
        E01=MFMA16(wpl[ 4*64+lane],hB00,E01); E01=MFMA16(wpl[ 5*64+lane],hB01,E01); E01=MFMA16(wpl[ 6*64+lane],hB02,E01); E01=MFMA16(wpl[ 7*64+lane],hB03,E01);
        E02=MFMA16(wpl[ 8*64+lane],hB00,E02); E02=MFMA16(wpl[ 9*64+lane],hB01,E02); E02=MFMA16(wpl[10*64+lane],hB02,E02); E02=MFMA16(wpl[11*64+lane],hB03,E02);
        E03=MFMA16(wpl[12*64+lane],hB00,E03); E03=MFMA16(wpl[13*64+lane],hB01,E03); E03=MFMA16(wpl[14*64+lane],hB02,E03); E03=MFMA16(wpl[15*64+lane],hB03,E03);
        E10=MFMA16(wpl[16*64+lane],hB10,E10); E10=MFMA16(wpl[17*64+lane],hB11,E10); E10=MFMA16(wpl[18*64+lane],hB12,E10); E10=MFMA16(wpl[19*64+lane],hB13,E10);
        E11=MFMA16(wpl[20*64+lane],hB10,E11); E11=MFMA16(wpl[21*64+lane],hB11,E11); E11=MFMA16(wpl[22*64+lane],hB12,E11); E11=MFMA16(wpl[23*64+lane],hB13,E11);
        E12=MFMA16(wpl[24*64+lane],hB10,E12); E12=MFMA16(wpl[25*64+lane],hB11,E12); E12=MFMA16(wpl[26*64+lane],hB12,E12); E12=MFMA16(wpl[27*64+lane],hB13,E12);
        E13=MFMA16(wpl[28*64+lane],hB10,E13); E13=MFMA16(wpl[29*64+lane],hB11,E13); E13=MFMA16(wpl[30*64+lane],hB12,E13); E13=MFMA16(wpl[31*64+lane],hB13,E13);
        // e -> f16 B-frags for gate1 (per-lane cvt); f32 E kept for fuse/LN
        h4 eB0 = pk4(E00), eB1 = pk4(E01), eB2 = pk4(E02), eB3 = pk4(E03);
        h4 eB4 = pk4(E10), eB5 = pk4(E11), eB6 = pk4(E12), eB7 = pk4(E13);
        // ---- gate1: g^T = Wg1^T @ [e0|e1]^T + bg1 (K=128 = 8 chunks) ----
        f4 G0 = *(f4*)(cstl + 128 + q4),      G1 = *(f4*)(cstl + 144 + q4);
        f4 G2 = *(f4*)(cstl + 160 + q4),      G3 = *(f4*)(cstl + 176 + q4);
        G0=MFMA16(wpl[2048+ 0*64+lane],eB0,G0); G0=MFMA16(wpl[2048+ 1*64+lane],eB1,G0);
        G0=MFMA16(wpl[2048+ 2*64+lane],eB2,G0); G0=MFMA16(wpl[2048+ 3*64+lane],eB3,G0);
        G0=MFMA16(wpl[2048+ 4*64+lane],eB4,G0); G0=MFMA16(wpl[2048+ 5*64+lane],eB5,G0);
        G0=MFMA16(wpl[2048+ 6*64+lane],eB6,G0); G0=MFMA16(wpl[2048+ 7*64+lane],eB7,G0);
        G1=MFMA16(wpl[2048+ 8*64+lane],eB0,G1); G1=MFMA16(wpl[2048+ 9*64+lane],eB1,G1);
        G1=MFMA16(wpl[2048+10*64+lane],eB2,G1); G1=MFMA16(wpl[2048+11*64+lane],eB3,G1);
        G1=MFMA16(wpl[2048+12*64+lane],eB4,G1); G1=MFMA16(wpl[2048+13*64+lane],eB5,G1);
        G1=MFMA16(wpl[2048+14*64+lane],eB6,G1); G1=MFMA16(wpl[2048+15*64+lane],eB7,G1);
        G2=MFMA16(wpl[2048+16*64+lane],eB0,G2); G2=MFMA16(wpl[2048+17*64+lane],eB1,G2);
        G2=MFMA16(wpl[2048+18*64+lane],eB2,G2); G2=MFMA16(wpl[2048+19*64+lane],eB3,G2);
        G2=MFMA16(wpl[2048+20*64+lane],eB4,G2); G2=MFMA16(wpl[2048+21*64+lane],eB5,G2);
        G2=MFMA16(wpl[2048+22*64+lane],eB6,G2); G2=MFMA16(wpl[2048+23*64+lane],eB7,G2);
        G3=MFMA16(wpl[2048+24*64+lane],eB0,G3); G3=MFMA16(wpl[2048+25*64+lane],eB1,G3);
        G3=MFMA16(wpl[2048+26*64+lane],eB2,G3); G3=MFMA16(wpl[2048+27*64+lane],eB3,G3);
        G3=MFMA16(wpl[2048+28*64+lane],eB4,G3); G3=MFMA16(wpl[2048+29*64+lane],eB5,G3);
        G3=MFMA16(wpl[2048+30*64+lane],eB6,G3); G3=MFMA16(wpl[2048+31*64+lane],eB7,G3);
        G0 = silu4(G0); G1 = silu4(G1); G2 = silu4(G2); G3 = silu4(G3);
        // ---- gate2 (VALU): logit diff = sum_v g[v]*wd[v], cross-quad via shfl ----
        f4 wd0 = *(f4*)(cstl + 192 + q4), wd1 = *(f4*)(cstl + 208 + q4);
        f4 wd2 = *(f4*)(cstl + 224 + q4), wd3 = *(f4*)(cstl + 240 + q4);
        f4 pv = G0*wd0 + G1*wd1 + G2*wd2 + G3*wd3;
        float part = (pv[0]+pv[1]) + (pv[2]+pv[3]);
        part += __shfl_xor(part, 16); part += __shfl_xor(part, 32);
        const float w1 = sig((part + dlgb)*invT);
        // ---- fuse + LayerNorm + head (f32, per-lane partials + 2 shfl each) ----
        f4 gw0 = *(f4*)(cstl + 256 + q4), gw1 = *(f4*)(cstl + 272 + q4);
        f4 gw2 = *(f4*)(cstl + 288 + q4), gw3 = *(f4*)(cstl + 304 + q4);
        f4 fu0 = E00 + w1*(E10-E00);
        f4 fu1 = E01 + w1*(E11-E01);
        f4 fu2 = E02 + w1*(E12-E02);
        f4 fu3 = E03 + w1*(E13-E03);
        f4 sfv = (fu0+fu1)+(fu2+fu3);
        float sv = (sfv[0]+sfv[1])+(sfv[2]+sfv[3]);
        f4 sfq = (fu0*fu0+fu1*fu1)+(fu2*fu2+fu3*fu3);
        float sq = (sfq[0]+sfq[1])+(sfq[2]+sfq[3]);
        f4 sfd = (fu0*gw0+fu1*gw1)+(fu2*gw2+fu3*gw3);
        float dt = (sfd[0]+sfd[1])+(sfd[2]+sfd[3]);
        sv += __shfl_xor(sv, 16); sv += __shfl_xor(sv, 32);
        sq += __shfl_xor(sq, 16); sq += __shfl_xor(sq, 32);
        dt += __shfl_xor(dt, 16); dt += __shfl_xor(dt, 32);
        const float mu = sv * (1.f/64.f);
        const float vv = sq * (1.f/64.f) - mu*mu;
        const float rs = __builtin_amdgcn_rsqf(vv + 1e-5f);
        const float o = fmaf(rs, dt - mu*C1, outc);
        if (lane < 16) out[p0 + lane] = o;
    }
}

extern "C" void kernel_launch(void* const* d_in, const int* in_sizes, int n_in,
                              void* d_out, int out_size, void* d_ws, size_t ws_size,
                              hipStream_t stream)
{
    const float* coords = (const float*)d_in[0];
    const float* cost   = (const float*)d_in[1];
    const float* lscale = (const float*)d_in[2];
    const float* W1     = (const float*)d_in[3];
    const float* b1     = (const float*)d_in[4];
    const float* W2     = (const float*)d_in[5];
    const float* b2     = (const float*)d_in[6];
    const float* fg     = (const float*)d_in[7];
    const float* fb     = (const float*)d_in[8];
    const float* Wg1    = (const float*)d_in[9];
    const float* bg1    = (const float*)d_in[10];
    const float* Wg2    = (const float*)d_in[11];
    const float* bg2    = (const float*)d_in[12];
    const float* gt     = (const float*)d_in[13];
    const float* lng    = (const float*)d_in[14];
    const float* lnb    = (const float*)d_in[15];
    const float* Wo     = (const float*)d_in[16];
    const float* bo     = (const float*)d_in[17];
    float* out = (float*)d_out;

    prep_kernel<<<20, 256, 0, stream>>>(W1, b1, W2, b2, fg, fb, Wg1, bg1, Wg2, lng, lnb, Wo);
    fused_kernel<<<BLOCKS, 256, 0, stream>>>(coords, cost, lscale, bg2, gt, bo, out);
}

// Round 16
// 135.328 us; speedup vs baseline: 1.2866x; 1.0132x over previous
//
#include <hip/hip_runtime.h>
#include <math.h>

typedef _Float16 h4 __attribute__((ext_vector_type(4)));
typedef __fp16   p2 __attribute__((ext_vector_type(2)));   // cvt_pkrtz result type
typedef float    f4 __attribute__((ext_vector_type(4)));

#define NPAIR (8*256*256)
#define NTILE (NPAIR/16)          // 32768 tiles of 16 pairs
#define BLOCKS 2048
#define ITERS (NTILE/(BLOCKS*4))  // 4 tiles per wave

// 16x16x16 f16 MFMA: C/D layout (row=4q+reg, col=lane&15) == B layout
// (k=4q+j, n=lane&15)  ->  layers chain in-register via per-lane cvt only.
#define MFMA16(a,b,c) __builtin_amdgcn_mfma_f32_16x16x16f16((a),(b),(c),0,0,0)
#define FENCE() asm volatile("" ::: "memory")

// A-fragment pool (h4 units, transposed weights: m=out-channel on lane&15,
// k=in-channel = 4q+j):
// [0,256)     W1^T  [t*64+lane]                 k<9 -> W1[k][16t+nn]; k==9 -> b1; else 0
// [256,2304)  W2'^T [((enc*4+ct)*4+kc)*64+lane] W2[16kc+4q+j][16ct+nn] * fg_enc[16ct+nn]
// [2304,4352) Wg1^T [(vt*8+kc)*64+lane]         Wg1[16kc+4q+j][16vt+nn]
__device__ h4 g_all[4352];
// Per-channel epilogue constants (c = 0..63):
// [0,64) b2*fg0+fb0  [64,128) b2*fg1+fb1  [128,192) bg1
// [192,256) Wg2[c][1]-Wg2[c][0]  [256,320) ln_g*Wo
__device__ float g_cst[320];
__device__ float g_cc[2];         // C0 = sum ln_b*Wo, C1 = sum ln_g*Wo

__global__ void prep_kernel(const float* __restrict__ W1, const float* __restrict__ b1,
                            const float* __restrict__ W2, const float* __restrict__ b2,
                            const float* __restrict__ fgam, const float* __restrict__ fbet,
                            const float* __restrict__ Wg1, const float* __restrict__ bg1,
                            const float* __restrict__ Wg2,
                            const float* __restrict__ ln_g, const float* __restrict__ ln_b,
                            const float* __restrict__ Wo)
{
    int idx = blockIdx.x * 256 + threadIdx.x;
    int lane = idx & 63, q = (lane >> 4), nn = lane & 15;
    if (idx < 256) {
        int t = idx >> 6;
        h4 v;
#pragma unroll
        for (int j = 0; j < 4; ++j) {
            int k = 4*q + j;
            float x = (k < 9) ? W1[k*64 + 16*t + nn] : (k == 9 ? b1[16*t + nn] : 0.f);
            v[j] = (_Float16)x;
        }
        g_all[idx] = v;
    } else if (idx < 2304) {
        int z = idx - 256; int g = z >> 6;          // g = (enc*4+ct)*4+kc
        int kc = g & 3, ct = (g >> 2) & 3, enc = g >> 4;
        h4 v;
#pragma unroll
        for (int j = 0; j < 4; ++j) {
            int k = 16*kc + 4*q + j, c = 16*ct + nn;
            v[j] = (_Float16)(W2[k*64 + c] * fgam[enc*64 + c]);
        }
        g_all[idx] = v;
    } else if (idx < 4352) {
        int z = idx - 2304; int g = z >> 6;         // g = vt*8+kc
        int kc = g & 7, vt = g >> 3;
        h4 v;
#pragma unroll
        for (int j = 0; j < 4; ++j) {
            int k = 16*kc + 4*q + j;
            v[j] = (_Float16)Wg1[k*64 + 16*vt + nn];
        }
        g_all[idx] = v;
    } else if (idx == 4352) {
        float c0 = 0.f, c1 = 0.f;
        for (int k = 0; k < 64; ++k) { c0 += ln_b[k]*Wo[k]; c1 += ln_g[k]*Wo[k]; }
        g_cc[0] = c0; g_cc[1] = c1;
    } else if (idx >= 4608 && idx < 4928) {
        int c = idx - 4608;
        float v;
        if (c < 64)        v = fmaf(b2[c], fgam[c], fbet[c]);
        else if (c < 128)  { int cc = c-64;  v = fmaf(b2[cc], fgam[64+cc], fbet[64+cc]); }
        else if (c < 192)  v = bg1[c-128];
        else if (c < 256)  { int cc = c-192; v = Wg2[2*cc+1] - Wg2[2*cc]; }
        else               { int cc = c-256; v = ln_g[cc]*Wo[cc]; }
        g_cst[c] = v;
    }
}

__device__ __forceinline__ float sig(float x) { return __builtin_amdgcn_rcpf(1.f + __expf(-x)); }

__device__ __forceinline__ f4 silu4(f4 v)
{
    f4 r; r[0] = v[0]*sig(v[0]); r[1] = v[1]*sig(v[1]); r[2] = v[2]*sig(v[2]); r[3] = v[3]*sig(v[3]);
    return r;
}

__device__ __forceinline__ h4 pk4(f4 v)   // f32x4 -> f16x4, 2x v_cvt_pkrtz
{
    p2 lo = __builtin_amdgcn_cvt_pkrtz(v[0], v[1]);
    p2 hi = __builtin_amdgcn_cvt_pkrtz(v[2], v[3]);
    h4 r; r[0] = (_Float16)lo[0]; r[1] = (_Float16)lo[1];
          r[2] = (_Float16)hi[0]; r[3] = (_Float16)hi[1];
    return r;
}

// R16 = R15 with bounds(256,4): R15's demand (60 arch VGPR + ~64 accum in the
// unified file ~ 124) now fits the 128-total cap, unlike R5/R6 (~256 demand).
// LDS 39424 also fits 4 blocks/CU. Single-knob A/B vs R15: occupancy 3->4
// waves/SIMD to fill the serial MFMA->silu->cvt chain's dependency bubbles.
__global__ __launch_bounds__(256, 4) void fused_kernel(
    const float* __restrict__ coords, const float* __restrict__ cost,
    const float* __restrict__ lscale, const float* __restrict__ bg2,
    const float* __restrict__ gt, const float* __restrict__ bo,
    float* __restrict__ out)
{
    __shared__ __align__(16) char smem[32768 + 1280 + 4*1280];
    const int tid = threadIdx.x;
    const int wave = tid >> 6, lane = tid & 63;
    const int q = lane >> 4, nn = lane & 15;
    const int q4 = q*4;

    h4* wpool = (h4*)smem;                    // [0,2048) W2', [2048,4096) Wg1
    for (int z = tid; z < 4096; z += 256) wpool[z] = g_all[256 + z];
    float* cpool = (float*)(smem + 32768);    // 320 epilogue consts
    for (int z = tid; z < 320; z += 256) cpool[z] = g_cst[z];
    __syncthreads();

    _Float16* U = (_Float16*)(smem + 34048 + wave*1280);  // feat: [enc][16 pairs][20]
    for (int z = lane; z < 320; z += 64) ((float*)U)[z] = 0.f;  // zero pads once

    // W1^T A-frags, register-resident (8 VGPRs)
    h4 w1a0 = g_all[lane], w1a1 = g_all[64+lane], w1a2 = g_all[128+lane], w1a3 = g_all[192+lane];

    const float dlgb = bg2[1] - bg2[0];
    const float s0 = __expf(lscale[0]), s1 = __expf(lscale[1]);
    const float invT = __expf(-gt[0]);
    const float outc = g_cc[0] + bo[0], C1 = g_cc[1];

    const int wgid = blockIdx.x*4 + wave;

    for (int it = 0; it < ITERS; ++it) {
        const int T = wgid + it*(BLOCKS*4);
        const int p0 = T*16;
        const int bb = p0 >> 16, ii = (p0 >> 8) & 255, j0 = p0 & 255;
        // ---- features: lanes 0-15 cost enc, 16-31 angle enc; 1 LDS hop ----
        const float xc = cost[p0 + nn];
        const float* cb = coords + (bb << 9);
        const float xi = cb[2*ii], yi = cb[2*ii+1];
        const float xj = cb[2*(j0+nn)], yj = cb[2*(j0+nn)+1];
        const float ang = atan2f(yi - yj, xi - xj);
        const int isA = q & 1;
        const float xv = isA ? ang : xc;
        const float sE = isA ? s1 : s0;
        FENCE();
        if (lane < 32) {
            const float sn1 = __sinf(xv), cs1 = __cosf(xv);
            const float sn2 = 2.f*sn1*cs1, cs2 = fmaf(-2.f*sn1, sn1, 1.f);
            const float sn4 = 2.f*sn2*cs2, cs4 = fmaf(-2.f*sn2, sn2, 1.f);
            const float sn8 = 2.f*sn4*cs4, cs8 = fmaf(-2.f*sn4, sn4, 1.f);
            _Float16* fp = U + isA*320 + nn*20;
            p2 p01 = __builtin_amdgcn_cvt_pkrtz(xv*sE,  sn1*sE);
            p2 p23 = __builtin_amdgcn_cvt_pkrtz(cs1*sE, sn2*sE);
            p2 p45 = __builtin_amdgcn_cvt_pkrtz(cs2*sE, sn4*sE);
            p2 p67 = __builtin_amdgcn_cvt_pkrtz(cs4*sE, sn8*sE);
            p2 p89 = __builtin_amdgcn_cvt_pkrtz(cs8*sE, 1.0f);  // k=9: homogeneous 1 (W1 row 9 = b1)
            h4 w0; w0[0]=(_Float16)p01[0]; w0[1]=(_Float16)p01[1];
                   w0[2]=(_Float16)p23[0]; w0[3]=(_Float16)p23[1];
            h4 w1; w1[0]=(_Float16)p45[0]; w1[1]=(_Float16)p45[1];
                   w1[2]=(_Float16)p67[0]; w1[3]=(_Float16)p67[1];
            *(h4*)(fp)     = w0;   // ds_write_b64
            *(h4*)(fp + 4) = w1;
            fp[8] = (_Float16)p89[0];   // cs8 term
            fp[9] = (_Float16)p89[1];   // homogeneous 1 -> W1 row 9 (= b1)
        }
        FENCE();
        // ---- L1: h^T = W1^T @ feat^T (K=16 covers 9 feats + bias-1) ----
        h4 fB0 = *(h4*)(U + nn*20 + q4);
        h4 fB1 = *(h4*)(U + 320 + nn*20 + q4);
        const f4 z4 = {0.f, 0.f, 0.f, 0.f};
        f4 H00 = MFMA16(w1a0, fB0, z4), H01 = MFMA16(w1a1, fB0, z4);
        f4 H02 = MFMA16(w1a2, fB0, z4), H03 = MFMA16(w1a3, fB0, z4);
        f4 H10 = MFMA16(w1a0, fB1, z4), H11 = MFMA16(w1a1, fB1, z4);
        f4 H12 = MFMA16(w1a2, fB1, z4), H13 = MFMA16(w1a3, fB1, z4);
        // silu -> f16 B-frags for L2 (pure per-lane cvt, no LDS)
        h4 hB00 = pk4(silu4(H00)), hB01 = pk4(silu4(H01)), hB02 = pk4(silu4(H02)), hB03 = pk4(silu4(H03));
        h4 hB10 = pk4(silu4(H10)), hB11 = pk4(silu4(H11)), hB12 = pk4(silu4(H12)), hB13 = pk4(silu4(H13));
        // launder pool index: block LICM from hoisting weight frags / consts to regs
        int wofs = 0; asm volatile("" : "+s"(wofs));
        const h4* wpl = wpool + wofs;
        const float* cstl = cpool + wofs;
        // ---- L2: e^T = W2'^T @ h^T + b2' (FiLM folded; C-init from LDS consts) ----
        f4 E00 = *(f4*)(cstl + q4),       E01 = *(f4*)(cstl + 16 + q4);
        f4 E02 = *(f4*)(cstl + 32 + q4),  E03 = *(f4*)(cstl + 48 + q4);
        f4 E10 = *(f4*)(cstl + 64 + q4),  E11 = *(f4*)(cstl + 80 + q4);
        f4 E12 = *(f4*)(cstl + 96 + q4),  E13 = *(f4*)(cstl + 112 + q4);
        E00=MFMA16(wpl[ 0*64+lane],hB00,E00); E00=MFMA16(wpl[ 1*64+lane],hB01,E00); E00=MFMA16(wpl[ 2*64+lane],hB02,E00); E00=MFMA16(wpl[ 3*64+lane],hB03,E00);
        E01=MFMA16(wpl[ 4*64+lane],hB00,E01); E01=MFMA16(wpl[ 5*64+lane],hB01,E01); E01=MFMA16(wpl[ 6*64+lane],hB02,E01); E01=MFMA16(wpl[ 7*64+lane],hB03,E01);
        E02=MFMA16(wpl[ 8*64+lane],hB00,E02); E02=MFMA16(wpl[ 9*64+lane],hB01,E02); E02=MFMA16(wpl[10*64+lane],hB02,E02); E02=MFMA16(wpl[11*64+lane],hB03,E02);
        E03=MFMA16(wpl[12*64+lane],hB00,E03); E03=MFMA16(wpl[13*64+lane],hB01,E03); E03=MFMA16(wpl[14*64+lane],hB02,E03); E03=MFMA16(wpl[15*64+lane],hB03,E03);
        E10=MFMA16(wpl[16*64+lane],hB10,E10); E10=MFMA16(wpl[17*64+lane],hB11,E10); E10=MFMA16(wpl[18*64+lane],hB12,E10); E10=MFMA16(wpl[19*64+lane],hB13,E10);
        E11=MFMA16(wpl[20*64+lane],hB10,E11); E11=MFMA16(wpl[21*64+lane],hB11,E11); E11=MFMA16(wpl[22*64+lane],hB12,E11); E11=MFMA16(wpl[23*64+lane],hB13,E11);
        E12=MFMA16(wpl[24*64+lane],hB10,E12); E12=MFMA16(wpl[25*64+lane],hB11,E12); E12=MFMA16(wpl[26*64+lane],hB12,E12); E12=MFMA16(wpl[27*64+lane],hB13,E12);
        E13=MFMA16(wpl[28*64+lane],hB10,E13); E13=MFMA16(wpl[29*64+lane],hB11,E13); E13=MFMA16(wpl[30*64+lane],hB12,E13); E13=MFMA16(wpl[31*64+lane],hB13,E13);
        // e -> f16 B-frags for gate1 (per-lane cvt); f32 E kept for fuse/LN
        h4 eB0 = pk4(E00), eB1 = pk4(E01), eB2 = pk4(E02), eB3 = pk4(E03);
        h4 eB4 = pk4(E10), eB5 = pk4(E11), eB6 = pk4(E12), eB7 = pk4(E13);
        // ---- gate1: g^T = Wg1^T @ [e0|e1]^T + bg1 (K=128 = 8 chunks) ----
        f4 G0 = *(f4*)(cstl + 128 + q4),      G1 = *(f4*)(cstl + 144 + q4);
        f4 G2 = *(f4*)(cstl + 160 + q4),      G3 = *(f4*)(cstl + 176 + q4);
        G0=MFMA16(wpl[2048+ 0*64+lane],eB0,G0); G0=MFMA16(wpl[2048+ 1*64+lane],eB1,G0);
        G0=MFMA16(wpl[2048+ 2*64+lane],eB2,G0); G0=MFMA16(wpl[2048+ 3*64+lane],eB3,G0);
        G0=MFMA16(wpl[2048+ 4*64+lane],eB4,G0); G0=MFMA16(wpl[2048+ 5*64+lane],eB5,G0);
        G0=MFMA16(wpl[2048+ 6*64+lane],eB6,G0); G0=MFMA16(wpl[2048+ 7*64+lane],eB7,G0);
        G1=MFMA16(wpl[2048+ 8*64+lane],eB0,G1); G1=MFMA16(wpl[2048+ 9*64+lane],eB1,G1);
        G1=MFMA16(wpl[2048+10*64+lane],eB2,G1); G1=MFMA16(wpl[2048+11*64+lane],eB3,G1);
        G1=MFMA16(wpl[2048+12*64+lane],eB4,G1); G1=MFMA16(wpl[2048+13*64+lane],eB5,G1);
        G1=MFMA16(wpl[2048+14*64+lane],eB6,G1); G1=MFMA16(wpl[2048+15*64+lane],eB7,G1);
        G2=MFMA16(wpl[2048+16*64+lane],eB0,G2); G2=MFMA16(wpl[2048+17*64+lane],eB1,G2);
        G2=MFMA16(wpl[2048+18*64+lane],eB2,G2); G2=MFMA16(wpl[2048+19*64+lane],eB3,G2);
        G2=MFMA16(wpl[2048+20*64+lane],eB4,G2); G2=MFMA16(wpl[2048+21*64+lane],eB5,G2);
        G2=MFMA16(wpl[2048+22*64+lane],eB6,G2); G2=MFMA16(wpl[2048+23*64+lane],eB7,G2);
        G3=MFMA16(wpl[2048+24*64+lane],eB0,G3); G3=MFMA16(wpl[2048+25*64+lane],eB1,G3);
        G3=MFMA16(wpl[2048+26*64+lane],eB2,G3); G3=MFMA16(wpl[2048+27*64+lane],eB3,G3);
        G3=MFMA16(wpl[2048+28*64+lane],eB4,G3); G3=MFMA16(wpl[2048+29*64+lane],eB5,G3);
        G3=MFMA16(wpl[2048+30*64+lane],eB6,G3); G3=MFMA16(wpl[2048+31*64+lane],eB7,G3);
        G0 = silu4(G0); G1 = silu4(G1); G2 = silu4(G2); G3 = silu4(G3);
        // ---- gate2 (VALU): logit diff = sum_v g[v]*wd[v], cross-quad via shfl ----
        f4 wd0 = *(f4*)(cstl + 192 + q4), wd1 = *(f4*)(cstl + 208 + q4);
        f4 wd2 = *(f4*)(cstl + 224 + q4), wd3 = *(f4*)(cstl + 240 + q4);
        f4 pv = G0*wd0 + G1*wd1 + G2*wd2 + G3*wd3;
        float part = (pv[0]+pv[1]) + (pv[2]+pv[3]);
        part += __shfl_xor(part, 16); part += __shfl_xor(part, 32);
        const float w1 = sig((part + dlgb)*invT);
        // ---- fuse + LayerNorm + head (f32, per-lane partials + 2 shfl each) ----
        f4 gw0 = *(f4*)(cstl + 256 + q4), gw1 = *(f4*)(cstl + 272 + q4);
        f4 gw2 = *(f4*)(cstl + 288 + q4), gw3 = *(f4*)(cstl + 304 + q4);
        f4 fu0 = E00 + w1*(E10-E00);
        f4 fu1 = E01 + w1*(E11-E01);
        f4 fu2 = E02 + w1*(E12-E02);
        f4 fu3 = E03 + w1*(E13-E03);
        f4 sfv = (fu0+fu1)+(fu2+fu3);
        float sv = (sfv[0]+sfv[1])+(sfv[2]+sfv[3]);
        f4 sfq = (fu0*fu0+fu1*fu1)+(fu2*fu2+fu3*fu3);
        float sq = (sfq[0]+sfq[1])+(sfq[2]+sfq[3]);
        f4 sfd = (fu0*gw0+fu1*gw1)+(fu2*gw2+fu3*gw3);
        float dt = (sfd[0]+sfd[1])+(sfd[2]+sfd[3]);
        sv += __shfl_xor(sv, 16); sv += __shfl_xor(sv, 32);
        sq += __shfl_xor(sq, 16); sq += __shfl_xor(sq, 32);
        dt += __shfl_xor(dt, 16); dt += __shfl_xor(dt, 32);
        const float mu = sv * (1.f/64.f);
        const float vv = sq * (1.f/64.f) - mu*mu;
        const float rs = __builtin_amdgcn_rsqf(vv + 1e-5f);
        const float o = fmaf(rs, dt - mu*C1, outc);
        if (lane < 16) out[p0 + lane] = o;
    }
}

extern "C" void kernel_launch(void* const* d_in, const int* in_sizes, int n_in,
                              void* d_out, int out_size, void* d_ws, size_t ws_size,
                              hipStream_t stream)
{
    const float* coords = (const float*)d_in[0];
    const float* cost   = (const float*)d_in[1];
    const float* lscale = (const float*)d_in[2];
    const float* W1     = (const float*)d_in[3];
    const float* b1     = (const float*)d_in[4];
    const float* W2     = (const float*)d_in[5];
    const float* b2     = (const float*)d_in[6];
    const float* fg     = (const float*)d_in[7];
    const float* fb     = (const float*)d_in[8];
    const float* Wg1    = (const float*)d_in[9];
    const float* bg1    = (const float*)d_in[10];
    const float* Wg2    = (const float*)d_in[11];
    const float* bg2    = (const float*)d_in[12];
    const float* gt     = (const float*)d_in[13];
    const float* lng    = (const float*)d_in[14];
    const float* lnb    = (const float*)d_in[15];
    const float* Wo     = (const float*)d_in[16];
    const float* bo     = (const float*)d_in[17];
    float* out = (float*)d_out;

    prep_kernel<<<20, 256, 0, stream>>>(W1, b1, W2, b2, fg, fb, Wg1, bg1, Wg2, lng, lnb, Wo);
    fused_kernel<<<BLOCKS, 256, 0, stream>>>(coords, cost, lscale, bg2, gt, bo, out);
}